// Round 2
// baseline (628.887 us; speedup 1.0000x reference)
//
#include <hip/hip_runtime.h>
#include <hip/hip_bf16.h>

#define B_ 4
#define N_ 2048
#define F_ 256
#define H_ 8
#define O_ 256

// log2(e)/16 folded into Q so softmax can use exp2f (exact softmax, monotone map)
#define SCALE_QK 0.09016844005556021f

typedef __attribute__((ext_vector_type(8))) short short8;
typedef __attribute__((ext_vector_type(4))) short s16x4;
typedef __attribute__((ext_vector_type(4))) float f32x4;
typedef __attribute__((ext_vector_type(4))) unsigned int u32x4;

static __device__ __forceinline__ float bf2f(short u) {
    unsigned int x = ((unsigned int)(unsigned short)u) << 16;
    return __builtin_bit_cast(float, x);
}
static __device__ __forceinline__ short f2bf(float f) {
    unsigned int x = __builtin_bit_cast(unsigned int, f);
    unsigned int lsb = (x >> 16) & 1u;
    x += 0x7fffu + lsb;
    return (short)(x >> 16);
}
static __device__ __forceinline__ unsigned int pkbf(float a, float b) {
    return (unsigned int)(unsigned short)f2bf(a) |
           ((unsigned int)(unsigned short)f2bf(b) << 16);
}

// async global->LDS 16B/lane; LDS dst is wave-uniform base + lane*16
static __device__ __forceinline__ void gld16(const short* g, short* l) {
    __builtin_amdgcn_global_load_lds(
        (const __attribute__((address_space(1))) void*)g,
        (__attribute__((address_space(3))) void*)l, 16, 0, 0);
}

// ---------------- f32 -> bf16 transpose: dst[c][r] = (bf16)src[r][c] ----
__global__ __launch_bounds__(256) void cvtT_kernel(const float* __restrict__ src,
                                                   short* __restrict__ dst,
                                                   int R, int C) {
    __shared__ short tile[32][33];
    src += (size_t)blockIdx.z * R * C;
    dst += (size_t)blockIdx.z * R * C;
    int tx = threadIdx.x, ty = threadIdx.y;           // 32 x 8
    int c0 = blockIdx.x * 32, r0 = blockIdx.y * 32;
#pragma unroll
    for (int j = 0; j < 4; j++) {
        int r = r0 + ty + j * 8;
        tile[ty + j * 8][tx] = f2bf(src[(size_t)r * C + c0 + tx]);
    }
    __syncthreads();
#pragma unroll
    for (int j = 0; j < 4; j++) {
        int c = c0 + ty + j * 8;
        dst[(size_t)c * R + r0 + tx] = tile[tx][ty + j * 8];
    }
}

// ---------------- f32 -> bf16 straight convert ----------------
__global__ __launch_bounds__(256) void cvt_kernel(const float* __restrict__ src,
                                                  short* __restrict__ dst, int n) {
    int i = blockIdx.x * 256 + threadIdx.x;
    if (n >= 2048) {
        size_t base = (size_t)i * 8;
#pragma unroll
        for (int j = 0; j < 8; j++) dst[base + j] = f2bf(src[base + j]);
    } else if (i < n) {
        dst[i] = f2bf(src[i]);
    }
}

// ---- 64-row MFMA GEMM tile, B^T input: C[m][n] = sum_k A[m][k]*Bt[n][k]
template <int NCT>
__device__ __forceinline__ void gemm64_bt(const short* __restrict__ A, int lda,
                                          const short* __restrict__ Bt, int ldb,
                                          float* __restrict__ C, int ldc,
                                          int K, const short* __restrict__ bias) {
    __shared__ short sA[64][72];
    __shared__ short sB[NCT * 16][72];
    int tid = threadIdx.x;
    int w = tid >> 6, l = tid & 63, lq = l & 15, quad = l >> 4;
    f32x4 acc[NCT];
#pragma unroll
    for (int i = 0; i < NCT; i++) acc[i] = (f32x4)(0.f);

    for (int kb = 0; kb < K; kb += 64) {
        __syncthreads();
#pragma unroll
        for (int i = 0; i < 2; i++) {
            int idx = tid + i * 256; int r = idx >> 3, c = (idx & 7) * 8;
            *(short8*)&sA[r][c] = *(const short8*)&A[(size_t)r * lda + kb + c];
        }
#pragma unroll
        for (int i = 0; i < NCT / 2; i++) {
            int idx = tid + i * 256; int r = idx >> 3, c = (idx & 7) * 8;
            *(short8*)&sB[r][c] = *(const short8*)&Bt[(size_t)r * ldb + kb + c];
        }
        __syncthreads();
#pragma unroll
        for (int kk = 0; kk < 2; kk++) {
            short8 af = *(const short8*)&sA[w * 16 + lq][kk * 32 + quad * 8];
#pragma unroll
            for (int ct = 0; ct < NCT; ct++) {
                short8 bf = *(const short8*)&sB[ct * 16 + lq][kk * 32 + quad * 8];
                acc[ct] = __builtin_amdgcn_mfma_f32_16x16x32_bf16(af, bf, acc[ct], 0, 0, 0);
            }
        }
    }
#pragma unroll
    for (int ct = 0; ct < NCT; ct++) {
        int col = ct * 16 + lq;
        float bv = bias ? bf2f(bias[col]) : 0.f;
#pragma unroll
        for (int r = 0; r < 4; r++) {
            int row = w * 16 + quad * 4 + r;
            C[(size_t)row * ldc + col] = acc[ct][r] + bv;
        }
    }
}

// out[m][o] = msgs[m][:] @ Wout + bias; grid (128,4) = 512 blocks -> 2/CU
__global__ __launch_bounds__(256) void out_kernel(const short* __restrict__ msgs,
                                                  const short* __restrict__ WoutT,
                                                  const short* __restrict__ bias,
                                                  float* __restrict__ out) {
    int mt = blockIdx.x, nt = blockIdx.y;
    gemm64_bt<4>(msgs + (size_t)mt * 64 * (H_ * F_), H_ * F_,
                 WoutT + (size_t)nt * 64 * (H_ * F_), H_ * F_,
                 out + (size_t)mt * 64 * O_ + nt * 64, O_,
                 H_ * F_, bias + nt * 64);
}

// ============ fused flash attention, double-buffered pipeline ============
// Block: 512 threads = 8 waves, 128 q (wave w owns q = q0 + w*16 + lq).
// BN=32 keys/iter (halved vs R0 to cut LDS 128->80 KB => 2 blocks/CU).
// S^T = K.Q^T (A = keys from kvf, B = Q regs); O^T = V^T.P^T (A = V^T from
// kvTf, B = P^T via register shuffles). Same XOR-swizzle idioms as R0,
// chunk keys reduced 8->4 for the 32-wide kvTf rows.
// LDS = 4x16KB (kvf pair + kvTf pair) + 16KB wbuf = 80 KB.

// stage key-tile KT: K rows [32][256] (XOR chunk^(r&31)) into KVF,
// V^T rows [256][32] (XOR chunk^(r&3)) into KVTF; 4 gld16/lane.
#define STAGE_KV(KT, KVF, KVTF) do {                                         \
    _Pragma("unroll")                                                        \
    for (int i_ = 0; i_ < 2; i_++) {                                         \
        int rk_ = w * 4 + i_ * 2 + (l >> 5);                                 \
        int bk_ = (l & 31) ^ (rk_ & 31);                                     \
        gld16(&Xb[(size_t)((KT) * 32 + rk_) * F_ + bk_ * 8],                 \
              &KVF[(w * 4 + i_ * 2) * 256]);                                 \
        int rt_ = w * 32 + i_ * 16 + (l >> 2);                               \
        int bt_ = (l & 3) ^ (rt_ & 3);                                       \
        gld16(&XTb[(size_t)rt_ * N_ + (KT) * 32 + bt_ * 8],                  \
              &KVTF[(w * 32 + i_ * 16) * 32]);                               \
    }                                                                        \
} while (0)

#define COMPUTE_KT(KVF, KVTF) do {                                           \
    f32x4 sacc[2];                                                           \
    _Pragma("unroll")                                                        \
    for (int ct = 0; ct < 2; ct++) sacc[ct] = (f32x4)(0.f);                  \
    __builtin_amdgcn_s_setprio(1);                                           \
    _Pragma("unroll")                                                        \
    for (int kk = 0; kk < 8; kk++) {                                         \
        _Pragma("unroll")                                                    \
        for (int ct = 0; ct < 2; ct++) {                                     \
            int arow = ct * 16 + lq;                                         \
            int ab = (kk * 4 + quad) ^ (arow & 31);                          \
            short8 af = *(const short8*)&KVF[arow * 256 + ab * 8];           \
            sacc[ct] = __builtin_amdgcn_mfma_f32_16x16x32_bf16(af, aq[kk], sacc[ct], 0, 0, 0); \
        }                                                                    \
    }                                                                        \
    __builtin_amdgcn_s_setprio(0);                                           \
    float mx = -INFINITY;                                                    \
    _Pragma("unroll")                                                        \
    for (int ct = 0; ct < 2; ct++)                                           \
        _Pragma("unroll")                                                    \
        for (int r_ = 0; r_ < 4; r_++) mx = fmaxf(mx, sacc[ct][r_]);         \
    mx = fmaxf(mx, __shfl_xor(mx, 16));                                      \
    mx = fmaxf(mx, __shfl_xor(mx, 32));                                      \
    float mn = fmaxf(m_q, mx);                                               \
    float alpha = exp2f(m_q - mn);                                           \
    m_q = mn;                                                                \
    float pv[2][4]; float s_ = 0.f;                                          \
    _Pragma("unroll")                                                        \
    for (int ct = 0; ct < 2; ct++)                                           \
        _Pragma("unroll")                                                    \
        for (int r_ = 0; r_ < 4; r_++) {                                     \
            pv[ct][r_] = exp2f(sacc[ct][r_] - mn);                           \
            s_ += pv[ct][r_];                                                \
        }                                                                    \
    s_ += __shfl_xor(s_, 16);                                                \
    s_ += __shfl_xor(s_, 32);                                                \
    l_q = l_q * alpha + s_;                                                  \
    if (!__all(alpha == 1.0f)) {                                             \
        _Pragma("unroll")                                                    \
        for (int ct = 0; ct < 16; ct++)                                      \
            _Pragma("unroll")                                                \
            for (int r_ = 0; r_ < 4; r_++) oacc[ct][r_] *= alpha;            \
    }                                                                        \
    unsigned int w2[2][2];                                                   \
    _Pragma("unroll")                                                        \
    for (int ct = 0; ct < 2; ct++) {                                         \
        w2[ct][0] = pkbf(pv[ct][0], pv[ct][1]);                              \
        w2[ct][1] = pkbf(pv[ct][2], pv[ct][3]);                              \
    }                                                                        \
    int sl0 = (2 * (quad & 1)) * 16 + lq;                                    \
    int sl1 = sl0 + 16;                                                      \
    bool hi = (quad >> 1) != 0;                                              \
    short8 pfrag;                                                            \
    {                                                                        \
        unsigned int u0 = __shfl((int)w2[0][0], sl0);                        \
        unsigned int u1 = __shfl((int)w2[0][1], sl0);                        \
        unsigned int u2 = __shfl((int)w2[0][0], sl1);                        \
        unsigned int u3 = __shfl((int)w2[0][1], sl1);                        \
        unsigned int v0 = __shfl((int)w2[1][0], sl0);                        \
        unsigned int v1 = __shfl((int)w2[1][1], sl0);                        \
        unsigned int v2 = __shfl((int)w2[1][0], sl1);                        \
        unsigned int v3 = __shfl((int)w2[1][1], sl1);                        \
        u32x4 pk = { hi ? v0 : u0, hi ? v1 : u1, hi ? v2 : u2, hi ? v3 : u3 }; \
        pfrag = __builtin_bit_cast(short8, pk);                              \
    }                                                                        \
    __builtin_amdgcn_s_setprio(1);                                           \
    _Pragma("unroll")                                                        \
    for (int ct = 0; ct < 16; ct++) {                                        \
        int arow = ct * 16 + lq;                                             \
        short8 a0 = *(const short8*)&KVTF[arow * 32 + (quad ^ (arow & 3)) * 8]; \
        oacc[ct] = __builtin_amdgcn_mfma_f32_16x16x32_bf16(a0, pfrag, oacc[ct], 0, 0, 0); \
    }                                                                        \
    __builtin_amdgcn_s_setprio(0);                                           \
} while (0)

__global__ __launch_bounds__(512, 4) void attn_kernel(const short* __restrict__ X,
                                                      const short* __restrict__ WhT,
                                                      const short* __restrict__ XT,
                                                      short* __restrict__ msgs) {
    __shared__ short kvfA[8192];    // 16 KB  [32 k][256 f]
    __shared__ short kvfB[8192];    // 16 KB
    __shared__ short kvTfA[8192];   // 16 KB  [256 f][32 k]
    __shared__ short kvTfB[8192];   // 16 KB
    __shared__ short wbuf[8192];    // 16 KB  [256 f_out][32 f_in] (phase 0 only)

    int qt = blockIdx.x, bh = blockIdx.y, b = bh >> 3, h = bh & 7;
    int tid = threadIdx.x, w = tid >> 6, l = tid & 63, lq = l & 15, quad = l >> 4;
    int q0 = qt * 128;

    const short* Xb  = X  + (size_t)b * N_ * F_;
    const short* XTb = XT + (size_t)b * F_ * N_;
    const short* Whh = WhT + (size_t)h * F_ * F_;

    f32x4 oacc[16];
    short8 aq[8];

    // ---------- phase 0: Q = (X qtile @ Wh) * SCALE_QK (128 q rows) ----------
    // X rows q0..q0+127 live in the 4 KV buffers as [32][256], XOR chunk^(r&31).
    // Wave w's 16 rows sit in buffer w>>1, local rows (w&1)*16..+15.
#pragma unroll
    for (int i = 0; i < 16; i++) oacc[i] = (f32x4)(0.f);
    short* xbuf = (w < 2) ? kvfA : (w < 4) ? kvfB : (w < 6) ? kvTfA : kvTfB;
#pragma unroll
    for (int i_ = 0; i_ < 8; i_++) {
        int rloc = (w & 1) * 16 + i_ * 2 + (l >> 5);     // local row in buffer
        int bk = (l & 31) ^ (rloc & 31);
        gld16(&Xb[(size_t)(q0 + w * 16 + i_ * 2 + (l >> 5)) * F_ + bk * 8],
              &xbuf[((w & 1) * 16 + i_ * 2) * 256]);
    }
#pragma unroll 1
    for (int kb = 0; kb < 8; kb++) {
        __syncthreads();   // prev kb's W reads done
#pragma unroll
        for (int i_ = 0; i_ < 2; i_++) {   // stage WhT[h][0:256][kb*32..+31]
            int rt_ = w * 32 + i_ * 16 + (l >> 2);
            int bt_ = (l & 3) ^ (rt_ & 3);
            gld16(&Whh[(size_t)rt_ * F_ + kb * 32 + bt_ * 8],
                  &wbuf[(w * 32 + i_ * 16) * 32]);
        }
        __syncthreads();   // drains DMA (X on kb==0, W always)
        int arow = (w & 1) * 16 + lq;
        int ab = (kb * 4 + quad) ^ (arow & 31);
        short8 af = *(const short8*)&xbuf[arow * 256 + ab * 8];
#pragma unroll
        for (int ct = 0; ct < 16; ct++) {
            int brow = ct * 16 + lq;
            int bb = quad ^ (brow & 3);
            short8 bf = *(const short8*)&wbuf[brow * 32 + bb * 8];
            oacc[ct] = __builtin_amdgcn_mfma_f32_16x16x32_bf16(af, bf, oacc[ct], 0, 0, 0);
        }
    }
    __syncthreads();   // all X reads done; reuse buffers for Q, XOR (col>>3)^(r&31)
    {
#pragma unroll
        for (int ct = 0; ct < 16; ct++) {
#pragma unroll
            for (int r = 0; r < 4; r++) {
                int row = (w & 1) * 16 + quad * 4 + r;
                int col = ct * 16 + lq;
                int pb = (col >> 3) ^ (row & 31);
                xbuf[row * 256 + pb * 8 + (col & 7)] = f2bf(oacc[ct][r] * SCALE_QK);
            }
        }
        __syncthreads();
#pragma unroll
        for (int kk = 0; kk < 8; kk++) {   // aq: B-frag Q[q=w*16+lq][kk*32+quad*8..]
            int row = (w & 1) * 16 + lq;
            int ab = (kk * 4 + quad) ^ (row & 31);
            aq[kk] = *(const short8*)&xbuf[row * 256 + ab * 8];
        }
    }
    __syncthreads();   // all aq reads done before tile-0 DMA overwrites buffers

    // ---------- phase 1: pipelined flash attention ----------
#pragma unroll
    for (int i = 0; i < 16; i++) oacc[i] = (f32x4)(0.f);
    float m_q = -INFINITY, l_q = 0.f;   // state for q = q0 + w*16 + lq

    STAGE_KV(0, kvfA, kvTfA);
    __syncthreads();   // drain tile-0 DMA

#pragma unroll 1
    for (int kt2 = 0; kt2 < 32; kt2++) {
        // half A: prefetch tile 2*kt2+1 -> B pair, compute from A pair
        STAGE_KV(2 * kt2 + 1, kvfB, kvTfB);
        COMPUTE_KT(kvfA, kvTfA);
        __syncthreads();   // all A-reads done + B-prefetch (issued pre-compute) drained
        // half B: prefetch tile (2*kt2+2)&63 -> A pair, compute from B pair
        STAGE_KV((2 * kt2 + 2) & 63, kvfA, kvTfA);   // last iter refetches tile 0 (unused, harmless)
        COMPUTE_KT(kvfB, kvTfB);
        __syncthreads();
    }

    // epilogue: per-lane q = q0 + w*16 + lq; feats ct*16 + quad*4 + r
    float inv = 1.f / l_q;
    short* Mout = msgs + (size_t)(b * N_ + q0 + w * 16 + lq) * (H_ * F_) + h * F_;
#pragma unroll
    for (int ct = 0; ct < 16; ct++) {
        s16x4 v4 = { f2bf(oacc[ct][0] * inv), f2bf(oacc[ct][1] * inv),
                     f2bf(oacc[ct][2] * inv), f2bf(oacc[ct][3] * inv) };
        *(s16x4*)&Mout[ct * 16 + quad * 4] = v4;
    }
}

extern "C" void kernel_launch(void* const* d_in, const int* in_sizes, int n_in,
                              void* d_out, int out_size, void* d_ws, size_t ws_size,
                              hipStream_t stream) {
    const float* nodes = (const float*)d_in[0];   // [4,2048,256] f32
    const float* Wh    = (const float*)d_in[1];   // [8,256,256]  f32
    const float* Wout  = (const float*)d_in[2];   // [2048,256]   f32
    const float* bias  = (const float*)d_in[3];   // [256]        f32
    float* out = (float*)d_out;                   // [4,2048,256] f32

    char* ws = (char*)d_ws;
    short* msgs   = (short*)(ws);                   // [8192][2048] bf16 = 32 MB
    short* WhT    = (short*)(ws + 33554432);        // [8][256][256]       1 MB
    short* WoutT  = (short*)(ws + 34603008);        // [256][2048]         1 MB
    short* XT     = (short*)(ws + 35651584);        // [4][256][2048]      4 MB
    short* Xbf    = (short*)(ws + 39845888);        // [4][2048][256]      4 MB
    short* biasbf = (short*)(ws + 44040192);        // [256]

    dim3 tblk(32, 8, 1);
    hipLaunchKernelGGL(cvtT_kernel, dim3(8, 8, 8),  tblk, 0, stream, Wh,    WhT,   256,  256);
    hipLaunchKernelGGL(cvtT_kernel, dim3(8, 64, 1), tblk, 0, stream, Wout,  WoutT, 2048, 256);
    hipLaunchKernelGGL(cvtT_kernel, dim3(8, 64, 4), tblk, 0, stream, nodes, XT,    2048, 256);
    hipLaunchKernelGGL(cvt_kernel,  dim3(1024), dim3(256), 0, stream, nodes, Xbf, 2097152);
    hipLaunchKernelGGL(cvt_kernel,  dim3(1),    dim3(256), 0, stream, bias, biasbf, 256);

    hipLaunchKernelGGL(attn_kernel, dim3(16, 32), dim3(512), 0, stream, Xbf, WhT, XT, msgs);
    hipLaunchKernelGGL(out_kernel,  dim3(128, 4), dim3(256), 0, stream, msgs, WoutT, biasbf, out);
}

// Round 3
// 620.892 us; speedup vs baseline: 1.0129x; 1.0129x over previous
//
#include <hip/hip_runtime.h>
#include <hip/hip_bf16.h>

#define B_ 4
#define N_ 2048
#define F_ 256
#define H_ 8
#define O_ 256

// log2(e)/16 folded into Q so softmax can use exp2f (exact softmax, monotone map)
#define SCALE_QK 0.09016844005556021f

typedef __attribute__((ext_vector_type(8))) short short8;
typedef __attribute__((ext_vector_type(4))) short s16x4;
typedef __attribute__((ext_vector_type(4))) float f32x4;
typedef __attribute__((ext_vector_type(4))) unsigned int u32x4;

static __device__ __forceinline__ float bf2f(short u) {
    unsigned int x = ((unsigned int)(unsigned short)u) << 16;
    return __builtin_bit_cast(float, x);
}
static __device__ __forceinline__ short f2bf(float f) {
    unsigned int x = __builtin_bit_cast(unsigned int, f);
    unsigned int lsb = (x >> 16) & 1u;
    x += 0x7fffu + lsb;
    return (short)(x >> 16);
}
static __device__ __forceinline__ unsigned int pkbf(float a, float b) {
    return (unsigned int)(unsigned short)f2bf(a) |
           ((unsigned int)(unsigned short)f2bf(b) << 16);
}

// async global->LDS 16B/lane; LDS dst is wave-uniform base + lane*16
static __device__ __forceinline__ void gld16(const short* g, short* l) {
    __builtin_amdgcn_global_load_lds(
        (const __attribute__((address_space(1))) void*)g,
        (__attribute__((address_space(3))) void*)l, 16, 0, 0);
}

// ---------------- f32 -> bf16 transpose: dst[c][r] = (bf16)src[r][c] ----
__global__ __launch_bounds__(256) void cvtT_kernel(const float* __restrict__ src,
                                                   short* __restrict__ dst,
                                                   int R, int C) {
    __shared__ short tile[32][33];
    src += (size_t)blockIdx.z * R * C;
    dst += (size_t)blockIdx.z * R * C;
    int tx = threadIdx.x, ty = threadIdx.y;           // 32 x 8
    int c0 = blockIdx.x * 32, r0 = blockIdx.y * 32;
#pragma unroll
    for (int j = 0; j < 4; j++) {
        int r = r0 + ty + j * 8;
        tile[ty + j * 8][tx] = f2bf(src[(size_t)r * C + c0 + tx]);
    }
    __syncthreads();
#pragma unroll
    for (int j = 0; j < 4; j++) {
        int c = c0 + ty + j * 8;
        dst[(size_t)c * R + r0 + tx] = tile[tx][ty + j * 8];
    }
}

// ---------------- f32 -> bf16 straight convert ----------------
__global__ __launch_bounds__(256) void cvt_kernel(const float* __restrict__ src,
                                                  short* __restrict__ dst, int n) {
    int i = blockIdx.x * 256 + threadIdx.x;
    if (n >= 2048) {
        size_t base = (size_t)i * 8;
#pragma unroll
        for (int j = 0; j < 8; j++) dst[base + j] = f2bf(src[base + j]);
    } else if (i < n) {
        dst[i] = f2bf(src[i]);
    }
}

// ---- 64-row MFMA GEMM tile, B^T input: C[m][n] = sum_k A[m][k]*Bt[n][k]
template <int NCT>
__device__ __forceinline__ void gemm64_bt(const short* __restrict__ A, int lda,
                                          const short* __restrict__ Bt, int ldb,
                                          float* __restrict__ C, int ldc,
                                          int K, const short* __restrict__ bias) {
    __shared__ short sA[64][72];
    __shared__ short sB[NCT * 16][72];
    int tid = threadIdx.x;
    int w = tid >> 6, l = tid & 63, lq = l & 15, quad = l >> 4;
    f32x4 acc[NCT];
#pragma unroll
    for (int i = 0; i < NCT; i++) acc[i] = (f32x4)(0.f);

    for (int kb = 0; kb < K; kb += 64) {
        __syncthreads();
#pragma unroll
        for (int i = 0; i < 2; i++) {
            int idx = tid + i * 256; int r = idx >> 3, c = (idx & 7) * 8;
            *(short8*)&sA[r][c] = *(const short8*)&A[(size_t)r * lda + kb + c];
        }
#pragma unroll
        for (int i = 0; i < NCT / 2; i++) {
            int idx = tid + i * 256; int r = idx >> 3, c = (idx & 7) * 8;
            *(short8*)&sB[r][c] = *(const short8*)&Bt[(size_t)r * ldb + kb + c];
        }
        __syncthreads();
#pragma unroll
        for (int kk = 0; kk < 2; kk++) {
            short8 af = *(const short8*)&sA[w * 16 + lq][kk * 32 + quad * 8];
#pragma unroll
            for (int ct = 0; ct < NCT; ct++) {
                short8 bf = *(const short8*)&sB[ct * 16 + lq][kk * 32 + quad * 8];
                acc[ct] = __builtin_amdgcn_mfma_f32_16x16x32_bf16(af, bf, acc[ct], 0, 0, 0);
            }
        }
    }
#pragma unroll
    for (int ct = 0; ct < NCT; ct++) {
        int col = ct * 16 + lq;
        float bv = bias ? bf2f(bias[col]) : 0.f;
#pragma unroll
        for (int r = 0; r < 4; r++) {
            int row = w * 16 + quad * 4 + r;
            C[(size_t)row * ldc + col] = acc[ct][r] + bv;
        }
    }
}

// out[m][o] = msgs[m][:] @ Wout + bias; grid (128,4) = 512 blocks -> 2/CU
__global__ __launch_bounds__(256) void out_kernel(const short* __restrict__ msgs,
                                                  const short* __restrict__ WoutT,
                                                  const short* __restrict__ bias,
                                                  float* __restrict__ out) {
    int mt = blockIdx.x, nt = blockIdx.y;
    gemm64_bt<4>(msgs + (size_t)mt * 64 * (H_ * F_), H_ * F_,
                 WoutT + (size_t)nt * 64 * (H_ * F_), H_ * F_,
                 out + (size_t)mt * 64 * O_ + nt * 64, O_,
                 H_ * F_, bias + nt * 64);
}

// ============ fused flash attention, double-buffered pipeline ============
// Block: 512 threads = 8 waves, 128 q (wave w owns q = q0 + w*16 + lq).
// BN=32 keys/iter; LDS 80 KB => 2 blocks/CU.
// XCD batch-locality swizzle: flat id = (qt*4 + (h>>1))*8 + b*2 + (h&1);
// with XCD = id%8 round-robin, XCD x serves ONLY batch b = x>>1 (and one
// head parity) -> per-XCD L2 working set ~2.6 MB < 4 MB, so K/V re-reads
// L2-hit even when the 2 co-resident blocks/CU drift out of lockstep.
// (R2 lesson: without this, 2/CU desync thrashed L2 -> 910 MB HBM fetch.)

// stage key-tile KT: K rows [32][256] (XOR chunk^(r&31)) into KVF,
// V^T rows [256][32] (XOR chunk^(r&3)) into KVTF; 4 gld16/lane.
#define STAGE_KV(KT, KVF, KVTF) do {                                         \
    _Pragma("unroll")                                                        \
    for (int i_ = 0; i_ < 2; i_++) {                                         \
        int rk_ = w * 4 + i_ * 2 + (l >> 5);                                 \
        int bk_ = (l & 31) ^ (rk_ & 31);                                     \
        gld16(&Xb[(size_t)((KT) * 32 + rk_) * F_ + bk_ * 8],                 \
              &KVF[(w * 4 + i_ * 2) * 256]);                                 \
        int rt_ = w * 32 + i_ * 16 + (l >> 2);                               \
        int bt_ = (l & 3) ^ (rt_ & 3);                                       \
        gld16(&XTb[(size_t)rt_ * N_ + (KT) * 32 + bt_ * 8],                  \
              &KVTF[(w * 32 + i_ * 16) * 32]);                               \
    }                                                                        \
} while (0)

#define COMPUTE_KT(KVF, KVTF) do {                                           \
    f32x4 sacc[2];                                                           \
    _Pragma("unroll")                                                        \
    for (int ct = 0; ct < 2; ct++) sacc[ct] = (f32x4)(0.f);                  \
    __builtin_amdgcn_s_setprio(1);                                           \
    _Pragma("unroll")                                                        \
    for (int kk = 0; kk < 8; kk++) {                                         \
        _Pragma("unroll")                                                    \
        for (int ct = 0; ct < 2; ct++) {                                     \
            int arow = ct * 16 + lq;                                         \
            int ab = (kk * 4 + quad) ^ (arow & 31);                          \
            short8 af = *(const short8*)&KVF[arow * 256 + ab * 8];           \
            sacc[ct] = __builtin_amdgcn_mfma_f32_16x16x32_bf16(af, aq[kk], sacc[ct], 0, 0, 0); \
        }                                                                    \
    }                                                                        \
    __builtin_amdgcn_s_setprio(0);                                           \
    float mx = -INFINITY;                                                    \
    _Pragma("unroll")                                                        \
    for (int ct = 0; ct < 2; ct++)                                           \
        _Pragma("unroll")                                                    \
        for (int r_ = 0; r_ < 4; r_++) mx = fmaxf(mx, sacc[ct][r_]);         \
    mx = fmaxf(mx, __shfl_xor(mx, 16));                                      \
    mx = fmaxf(mx, __shfl_xor(mx, 32));                                      \
    float mn = fmaxf(m_q, mx);                                               \
    float alpha = exp2f(m_q - mn);                                           \
    m_q = mn;                                                                \
    float pv[2][4]; float s_ = 0.f;                                          \
    _Pragma("unroll")                                                        \
    for (int ct = 0; ct < 2; ct++)                                           \
        _Pragma("unroll")                                                    \
        for (int r_ = 0; r_ < 4; r_++) {                                     \
            pv[ct][r_] = exp2f(sacc[ct][r_] - mn);                           \
            s_ += pv[ct][r_];                                                \
        }                                                                    \
    s_ += __shfl_xor(s_, 16);                                                \
    s_ += __shfl_xor(s_, 32);                                                \
    l_q = l_q * alpha + s_;                                                  \
    if (!__all(alpha == 1.0f)) {                                             \
        _Pragma("unroll")                                                    \
        for (int ct = 0; ct < 16; ct++)                                      \
            _Pragma("unroll")                                                \
            for (int r_ = 0; r_ < 4; r_++) oacc[ct][r_] *= alpha;            \
    }                                                                        \
    unsigned int w2[2][2];                                                   \
    _Pragma("unroll")                                                        \
    for (int ct = 0; ct < 2; ct++) {                                         \
        w2[ct][0] = pkbf(pv[ct][0], pv[ct][1]);                              \
        w2[ct][1] = pkbf(pv[ct][2], pv[ct][3]);                              \
    }                                                                        \
    int sl0 = (2 * (quad & 1)) * 16 + lq;                                    \
    int sl1 = sl0 + 16;                                                      \
    bool hi = (quad >> 1) != 0;                                              \
    short8 pfrag;                                                            \
    {                                                                        \
        unsigned int u0 = __shfl((int)w2[0][0], sl0);                        \
        unsigned int u1 = __shfl((int)w2[0][1], sl0);                        \
        unsigned int u2 = __shfl((int)w2[0][0], sl1);                        \
        unsigned int u3 = __shfl((int)w2[0][1], sl1);                        \
        unsigned int v0 = __shfl((int)w2[1][0], sl0);                        \
        unsigned int v1 = __shfl((int)w2[1][1], sl0);                        \
        unsigned int v2 = __shfl((int)w2[1][0], sl1);                        \
        unsigned int v3 = __shfl((int)w2[1][1], sl1);                        \
        u32x4 pk = { hi ? v0 : u0, hi ? v1 : u1, hi ? v2 : u2, hi ? v3 : u3 }; \
        pfrag = __builtin_bit_cast(short8, pk);                              \
    }                                                                        \
    __builtin_amdgcn_s_setprio(1);                                           \
    _Pragma("unroll")                                                        \
    for (int ct = 0; ct < 16; ct++) {                                        \
        int arow = ct * 16 + lq;                                             \
        short8 a0 = *(const short8*)&KVTF[arow * 32 + (quad ^ (arow & 3)) * 8]; \
        oacc[ct] = __builtin_amdgcn_mfma_f32_16x16x32_bf16(a0, pfrag, oacc[ct], 0, 0, 0); \
    }                                                                        \
    __builtin_amdgcn_s_setprio(0);                                           \
} while (0)

__global__ __launch_bounds__(512, 4) void attn_kernel(const short* __restrict__ X,
                                                      const short* __restrict__ WhT,
                                                      const short* __restrict__ XT,
                                                      short* __restrict__ msgs) {
    __shared__ short kvfA[8192];    // 16 KB  [32 k][256 f]
    __shared__ short kvfB[8192];    // 16 KB
    __shared__ short kvTfA[8192];   // 16 KB  [256 f][32 k]
    __shared__ short kvTfB[8192];   // 16 KB
    __shared__ short wbuf[8192];    // 16 KB  [256 f_out][32 f_in] (phase 0 only)

    // batch-locality decode: id%8 = b*2+(h&1) -> XCD x>>1 owns batch b
    int id = blockIdx.x;
    int low = id & 7, top = id >> 3;
    int b = low >> 1, hl = low & 1;
    int qt = top >> 2, h = (top & 3) * 2 + hl;

    int tid = threadIdx.x, w = tid >> 6, l = tid & 63, lq = l & 15, quad = l >> 4;
    int q0 = qt * 128;

    const short* Xb  = X  + (size_t)b * N_ * F_;
    const short* XTb = XT + (size_t)b * F_ * N_;
    const short* Whh = WhT + (size_t)h * F_ * F_;

    f32x4 oacc[16];
    short8 aq[8];

    // ---------- phase 0: Q = (X qtile @ Wh) * SCALE_QK (128 q rows) ----------
    // X rows q0..q0+127 live in the 4 KV buffers as [32][256], XOR chunk^(r&31).
    // Wave w's 16 rows sit in buffer w>>1, local rows (w&1)*16..+15.
#pragma unroll
    for (int i = 0; i < 16; i++) oacc[i] = (f32x4)(0.f);
    short* xbuf = (w < 2) ? kvfA : (w < 4) ? kvfB : (w < 6) ? kvTfA : kvTfB;
#pragma unroll
    for (int i_ = 0; i_ < 8; i_++) {
        int rloc = (w & 1) * 16 + i_ * 2 + (l >> 5);     // local row in buffer
        int bk = (l & 31) ^ (rloc & 31);
        gld16(&Xb[(size_t)(q0 + w * 16 + i_ * 2 + (l >> 5)) * F_ + bk * 8],
              &xbuf[((w & 1) * 16 + i_ * 2) * 256]);
    }
#pragma unroll 1
    for (int kb = 0; kb < 8; kb++) {
        __syncthreads();   // prev kb's W reads done
#pragma unroll
        for (int i_ = 0; i_ < 2; i_++) {   // stage WhT[h][0:256][kb*32..+31]
            int rt_ = w * 32 + i_ * 16 + (l >> 2);
            int bt_ = (l & 3) ^ (rt_ & 3);
            gld16(&Whh[(size_t)rt_ * F_ + kb * 32 + bt_ * 8],
                  &wbuf[(w * 32 + i_ * 16) * 32]);
        }
        __syncthreads();   // drains DMA (X on kb==0, W always)
        int arow = (w & 1) * 16 + lq;
        int ab = (kb * 4 + quad) ^ (arow & 31);
        short8 af = *(const short8*)&xbuf[arow * 256 + ab * 8];
#pragma unroll
        for (int ct = 0; ct < 16; ct++) {
            int brow = ct * 16 + lq;
            int bb = quad ^ (brow & 3);
            short8 bf = *(const short8*)&wbuf[brow * 32 + bb * 8];
            oacc[ct] = __builtin_amdgcn_mfma_f32_16x16x32_bf16(af, bf, oacc[ct], 0, 0, 0);
        }
    }
    __syncthreads();   // all X reads done; reuse buffers for Q, XOR (col>>3)^(r&31)
    {
#pragma unroll
        for (int ct = 0; ct < 16; ct++) {
#pragma unroll
            for (int r = 0; r < 4; r++) {
                int row = (w & 1) * 16 + quad * 4 + r;
                int col = ct * 16 + lq;
                int pb = (col >> 3) ^ (row & 31);
                xbuf[row * 256 + pb * 8 + (col & 7)] = f2bf(oacc[ct][r] * SCALE_QK);
            }
        }
        __syncthreads();
#pragma unroll
        for (int kk = 0; kk < 8; kk++) {   // aq: B-frag Q[q=w*16+lq][kk*32+quad*8..]
            int row = (w & 1) * 16 + lq;
            int ab = (kk * 4 + quad) ^ (row & 31);
            aq[kk] = *(const short8*)&xbuf[row * 256 + ab * 8];
        }
    }
    __syncthreads();   // all aq reads done before tile-0 DMA overwrites buffers

    // ---------- phase 1: pipelined flash attention ----------
#pragma unroll
    for (int i = 0; i < 16; i++) oacc[i] = (f32x4)(0.f);
    float m_q = -INFINITY, l_q = 0.f;   // state for q = q0 + w*16 + lq

    STAGE_KV(0, kvfA, kvTfA);
    __syncthreads();   // drain tile-0 DMA

#pragma unroll 1
    for (int kt2 = 0; kt2 < 32; kt2++) {
        // half A: prefetch tile 2*kt2+1 -> B pair, compute from A pair
        STAGE_KV(2 * kt2 + 1, kvfB, kvTfB);
        COMPUTE_KT(kvfA, kvTfA);
        __syncthreads();   // all A-reads done + B-prefetch (issued pre-compute) drained
        // half B: prefetch tile (2*kt2+2)&63 -> A pair, compute from B pair
        STAGE_KV((2 * kt2 + 2) & 63, kvfA, kvTfA);   // last iter refetches tile 0 (unused, harmless)
        COMPUTE_KT(kvfB, kvTfB);
        __syncthreads();
    }

    // epilogue: per-lane q = q0 + w*16 + lq; feats ct*16 + quad*4 + r
    float inv = 1.f / l_q;
    short* Mout = msgs + (size_t)(b * N_ + q0 + w * 16 + lq) * (H_ * F_) + h * F_;
#pragma unroll
    for (int ct = 0; ct < 16; ct++) {
        s16x4 v4 = { f2bf(oacc[ct][0] * inv), f2bf(oacc[ct][1] * inv),
                     f2bf(oacc[ct][2] * inv), f2bf(oacc[ct][3] * inv) };
        *(s16x4*)&Mout[ct * 16 + quad * 4] = v4;
    }
}

extern "C" void kernel_launch(void* const* d_in, const int* in_sizes, int n_in,
                              void* d_out, int out_size, void* d_ws, size_t ws_size,
                              hipStream_t stream) {
    const float* nodes = (const float*)d_in[0];   // [4,2048,256] f32
    const float* Wh    = (const float*)d_in[1];   // [8,256,256]  f32
    const float* Wout  = (const float*)d_in[2];   // [2048,256]   f32
    const float* bias  = (const float*)d_in[3];   // [256]        f32
    float* out = (float*)d_out;                   // [4,2048,256] f32

    char* ws = (char*)d_ws;
    short* msgs   = (short*)(ws);                   // [8192][2048] bf16 = 32 MB
    short* WhT    = (short*)(ws + 33554432);        // [8][256][256]       1 MB
    short* WoutT  = (short*)(ws + 34603008);        // [256][2048]         1 MB
    short* XT     = (short*)(ws + 35651584);        // [4][256][2048]      4 MB
    short* Xbf    = (short*)(ws + 39845888);        // [4][2048][256]      4 MB
    short* biasbf = (short*)(ws + 44040192);        // [256]

    dim3 tblk(32, 8, 1);
    hipLaunchKernelGGL(cvtT_kernel, dim3(8, 8, 8),  tblk, 0, stream, Wh,    WhT,   256,  256);
    hipLaunchKernelGGL(cvtT_kernel, dim3(8, 64, 1), tblk, 0, stream, Wout,  WoutT, 2048, 256);
    hipLaunchKernelGGL(cvtT_kernel, dim3(8, 64, 4), tblk, 0, stream, nodes, XT,    2048, 256);
    hipLaunchKernelGGL(cvt_kernel,  dim3(1024), dim3(256), 0, stream, nodes, Xbf, 2097152);
    hipLaunchKernelGGL(cvt_kernel,  dim3(1),    dim3(256), 0, stream, bias, biasbf, 256);

    hipLaunchKernelGGL(attn_kernel, dim3(512), dim3(512), 0, stream, Xbf, WhT, XT, msgs);
    hipLaunchKernelGGL(out_kernel,  dim3(128, 4), dim3(256), 0, stream, msgs, WoutT, biasbf, out);
}

// Round 4
// 389.720 us; speedup vs baseline: 1.6137x; 1.5932x over previous
//
#include <hip/hip_runtime.h>
#include <hip/hip_bf16.h>

#define B_ 4
#define N_ 2048
#define F_ 256
#define H_ 8
#define O_ 256

// log2(e)/16 folded into Q so softmax can use exp2f (exact softmax, monotone map)
#define SCALE_QK 0.09016844005556021f

typedef __attribute__((ext_vector_type(8))) short short8;
typedef __attribute__((ext_vector_type(4))) short s16x4;
typedef __attribute__((ext_vector_type(4))) float f32x4;
typedef __attribute__((ext_vector_type(4))) unsigned int u32x4;

static __device__ __forceinline__ float bf2f(short u) {
    unsigned int x = ((unsigned int)(unsigned short)u) << 16;
    return __builtin_bit_cast(float, x);
}
static __device__ __forceinline__ short f2bf(float f) {
    unsigned int x = __builtin_bit_cast(unsigned int, f);
    unsigned int lsb = (x >> 16) & 1u;
    x += 0x7fffu + lsb;
    return (short)(x >> 16);
}
static __device__ __forceinline__ unsigned int pkbf(float a, float b) {
    return (unsigned int)(unsigned short)f2bf(a) |
           ((unsigned int)(unsigned short)f2bf(b) << 16);
}

// async global->LDS 16B/lane; LDS dst is wave-uniform base + lane*16
static __device__ __forceinline__ void gld16(const short* g, short* l) {
    __builtin_amdgcn_global_load_lds(
        (const __attribute__((address_space(1))) void*)g,
        (__attribute__((address_space(3))) void*)l, 16, 0, 0);
}

// ---------------- f32 -> bf16 transpose: dst[c][r] = (bf16)src[r][c] ----
__global__ __launch_bounds__(256) void cvtT_kernel(const float* __restrict__ src,
                                                   short* __restrict__ dst,
                                                   int R, int C) {
    __shared__ short tile[32][33];
    src += (size_t)blockIdx.z * R * C;
    dst += (size_t)blockIdx.z * R * C;
    int tx = threadIdx.x, ty = threadIdx.y;           // 32 x 8
    int c0 = blockIdx.x * 32, r0 = blockIdx.y * 32;
#pragma unroll
    for (int j = 0; j < 4; j++) {
        int r = r0 + ty + j * 8;
        tile[ty + j * 8][tx] = f2bf(src[(size_t)r * C + c0 + tx]);
    }
    __syncthreads();
#pragma unroll
    for (int j = 0; j < 4; j++) {
        int c = c0 + ty + j * 8;
        dst[(size_t)c * R + r0 + tx] = tile[tx][ty + j * 8];
    }
}

// ---------------- f32 -> bf16 straight convert ----------------
__global__ __launch_bounds__(256) void cvt_kernel(const float* __restrict__ src,
                                                  short* __restrict__ dst, int n) {
    int i = blockIdx.x * 256 + threadIdx.x;
    if (n >= 2048) {
        size_t base = (size_t)i * 8;
#pragma unroll
        for (int j = 0; j < 8; j++) dst[base + j] = f2bf(src[base + j]);
    } else if (i < n) {
        dst[i] = f2bf(src[i]);
    }
}

// ---- 64-row MFMA GEMM tile, B^T input: C[m][n] = sum_k A[m][k]*Bt[n][k]
template <int NCT>
__device__ __forceinline__ void gemm64_bt(const short* __restrict__ A, int lda,
                                          const short* __restrict__ Bt, int ldb,
                                          float* __restrict__ C, int ldc,
                                          int K, const short* __restrict__ bias) {
    __shared__ short sA[64][72];
    __shared__ short sB[NCT * 16][72];
    int tid = threadIdx.x;
    int w = tid >> 6, l = tid & 63, lq = l & 15, quad = l >> 4;
    f32x4 acc[NCT];
#pragma unroll
    for (int i = 0; i < NCT; i++) acc[i] = (f32x4)(0.f);

    for (int kb = 0; kb < K; kb += 64) {
        __syncthreads();
#pragma unroll
        for (int i = 0; i < 2; i++) {
            int idx = tid + i * 256; int r = idx >> 3, c = (idx & 7) * 8;
            *(short8*)&sA[r][c] = *(const short8*)&A[(size_t)r * lda + kb + c];
        }
#pragma unroll
        for (int i = 0; i < NCT / 2; i++) {
            int idx = tid + i * 256; int r = idx >> 3, c = (idx & 7) * 8;
            *(short8*)&sB[r][c] = *(const short8*)&Bt[(size_t)r * ldb + kb + c];
        }
        __syncthreads();
#pragma unroll
        for (int kk = 0; kk < 2; kk++) {
            short8 af = *(const short8*)&sA[w * 16 + lq][kk * 32 + quad * 8];
#pragma unroll
            for (int ct = 0; ct < NCT; ct++) {
                short8 bf = *(const short8*)&sB[ct * 16 + lq][kk * 32 + quad * 8];
                acc[ct] = __builtin_amdgcn_mfma_f32_16x16x32_bf16(af, bf, acc[ct], 0, 0, 0);
            }
        }
    }
#pragma unroll
    for (int ct = 0; ct < NCT; ct++) {
        int col = ct * 16 + lq;
        float bv = bias ? bf2f(bias[col]) : 0.f;
#pragma unroll
        for (int r = 0; r < 4; r++) {
            int row = w * 16 + quad * 4 + r;
            C[(size_t)row * ldc + col] = acc[ct][r] + bv;
        }
    }
}

// out[m][o] = msgs[m][:] @ Wout + bias; grid (128,4) = 512 blocks -> 2/CU
__global__ __launch_bounds__(256) void out_kernel(const short* __restrict__ msgs,
                                                  const short* __restrict__ WoutT,
                                                  const short* __restrict__ bias,
                                                  float* __restrict__ out) {
    int mt = blockIdx.x, nt = blockIdx.y;
    gemm64_bt<4>(msgs + (size_t)mt * 64 * (H_ * F_), H_ * F_,
                 WoutT + (size_t)nt * 64 * (H_ * F_), H_ * F_,
                 out + (size_t)mt * 64 * O_ + nt * 64, O_,
                 H_ * F_, bias + nt * 64);
}

// ============ fused flash attention, double-buffered, 2 HEADS/BLOCK ======
// Block: 512 threads = 8 waves, 128 q rows, TWO heads (h0, h0+1).
// 1 block/CU (LDS 128 KB) -- R2/R3 lesson: 2 blocks/CU desyncs the K/V
// sweep and thrashes the caches (FETCH 41 MB -> 900 MB) regardless of
// XCD swizzle; lockstep 1/CU is load-bearing. Instead amortize: the K/V
// streams are head-independent, so one staging pass + one barrier pair
// feeds 2x MFMA work (128/tile), and the two heads' independent softmax
// chains overlap VALU with the other head's MFMAs.
// S^T = K.Q^T (A = keys from LDS, B = Q regs); O^T = V^T.P^T.

// stage key-tile KT: K rows into KVF [64][256] (XOR b^(r&31)),
// V^T rows into KVTF [256][64] (XOR b^(r&7)); 8 waves, 8 gld16/lane.
#define STAGE_KV(KT, KVF, KVTF) do {                                         \
    _Pragma("unroll")                                                        \
    for (int i_ = 0; i_ < 4; i_++) {                                         \
        int rk_ = w * 8 + i_ * 2 + (l >> 5);                                 \
        int bk_ = (l & 31) ^ (rk_ & 31);                                     \
        gld16(&Xb[(size_t)((KT) * 64 + rk_) * F_ + bk_ * 8],                 \
              &KVF[(w * 8 + i_ * 2) * 256]);                                 \
        int rt_ = w * 32 + i_ * 8 + (l >> 3);                                \
        int bt_ = (l & 7) ^ (rt_ & 7);                                       \
        gld16(&XTb[(size_t)rt_ * N_ + (KT) * 64 + bt_ * 8],                  \
              &KVTF[(w * 32 + i_ * 8) * 64]);                                \
    }                                                                        \
} while (0)

#define COMPUTE_KT(KVF, KVTF) do {                                           \
    f32x4 sacc[2][4];                                                        \
    _Pragma("unroll")                                                        \
    for (int hh = 0; hh < 2; hh++)                                           \
        _Pragma("unroll")                                                    \
        for (int ct = 0; ct < 4; ct++) sacc[hh][ct] = (f32x4)(0.f);          \
    __builtin_amdgcn_s_setprio(1);                                           \
    _Pragma("unroll")                                                        \
    for (int kk = 0; kk < 8; kk++) {                                         \
        _Pragma("unroll")                                                    \
        for (int ct = 0; ct < 4; ct++) {                                     \
            int arow = ct * 16 + lq;                                         \
            int ab = (kk * 4 + quad) ^ (arow & 31);                          \
            short8 af = *(const short8*)&KVF[arow * 256 + ab * 8];           \
            sacc[0][ct] = __builtin_amdgcn_mfma_f32_16x16x32_bf16(af, aq[0][kk], sacc[0][ct], 0, 0, 0); \
            sacc[1][ct] = __builtin_amdgcn_mfma_f32_16x16x32_bf16(af, aq[1][kk], sacc[1][ct], 0, 0, 0); \
        }                                                                    \
    }                                                                        \
    __builtin_amdgcn_s_setprio(0);                                           \
    short8 pfrag[2][2];                                                      \
    int sl0 = (2 * (quad & 1)) * 16 + lq;                                    \
    int sl1 = sl0 + 16;                                                      \
    bool hi = (quad >> 1) != 0;                                              \
    _Pragma("unroll")                                                        \
    for (int hh = 0; hh < 2; hh++) {                                         \
        float mx = -INFINITY;                                                \
        _Pragma("unroll")                                                    \
        for (int ct = 0; ct < 4; ct++)                                       \
            _Pragma("unroll")                                                \
            for (int r_ = 0; r_ < 4; r_++) mx = fmaxf(mx, sacc[hh][ct][r_]); \
        mx = fmaxf(mx, __shfl_xor(mx, 16));                                  \
        mx = fmaxf(mx, __shfl_xor(mx, 32));                                  \
        float mn = fmaxf(m_q[hh], mx);                                       \
        float alpha = exp2f(m_q[hh] - mn);                                   \
        m_q[hh] = mn;                                                        \
        float pv[4][4]; float s_ = 0.f;                                      \
        _Pragma("unroll")                                                    \
        for (int ct = 0; ct < 4; ct++)                                       \
            _Pragma("unroll")                                                \
            for (int r_ = 0; r_ < 4; r_++) {                                 \
                pv[ct][r_] = exp2f(sacc[hh][ct][r_] - mn);                   \
                s_ += pv[ct][r_];                                            \
            }                                                                \
        s_ += __shfl_xor(s_, 16);                                            \
        s_ += __shfl_xor(s_, 32);                                            \
        l_q[hh] = l_q[hh] * alpha + s_;                                      \
        if (!__all(alpha == 1.0f)) {                                         \
            _Pragma("unroll")                                                \
            for (int ct = 0; ct < 16; ct++)                                  \
                _Pragma("unroll")                                            \
                for (int r_ = 0; r_ < 4; r_++) oacc[hh][ct][r_] *= alpha;    \
        }                                                                    \
        unsigned int w2[4][2];                                               \
        _Pragma("unroll")                                                    \
        for (int ct = 0; ct < 4; ct++) {                                     \
            w2[ct][0] = pkbf(pv[ct][0], pv[ct][1]);                          \
            w2[ct][1] = pkbf(pv[ct][2], pv[ct][3]);                          \
        }                                                                    \
        _Pragma("unroll")                                                    \
        for (int kk = 0; kk < 2; kk++) {                                     \
            unsigned int u0 = __shfl((int)w2[2 * kk][0], sl0);               \
            unsigned int u1 = __shfl((int)w2[2 * kk][1], sl0);               \
            unsigned int u2 = __shfl((int)w2[2 * kk][0], sl1);               \
            unsigned int u3 = __shfl((int)w2[2 * kk][1], sl1);               \
            unsigned int v0 = __shfl((int)w2[2 * kk + 1][0], sl0);           \
            unsigned int v1 = __shfl((int)w2[2 * kk + 1][1], sl0);           \
            unsigned int v2 = __shfl((int)w2[2 * kk + 1][0], sl1);           \
            unsigned int v3 = __shfl((int)w2[2 * kk + 1][1], sl1);           \
            u32x4 pk = { hi ? v0 : u0, hi ? v1 : u1, hi ? v2 : u2, hi ? v3 : u3 }; \
            pfrag[hh][kk] = __builtin_bit_cast(short8, pk);                  \
        }                                                                    \
    }                                                                        \
    __builtin_amdgcn_s_setprio(1);                                           \
    _Pragma("unroll")                                                        \
    for (int ct = 0; ct < 16; ct++) {                                        \
        int arow = ct * 16 + lq;                                             \
        short8 a0 = *(const short8*)&KVTF[arow * 64 + ((quad) ^ (arow & 7)) * 8]; \
        short8 a1 = *(const short8*)&KVTF[arow * 64 + ((4 + quad) ^ (arow & 7)) * 8]; \
        oacc[0][ct] = __builtin_amdgcn_mfma_f32_16x16x32_bf16(a0, pfrag[0][0], oacc[0][ct], 0, 0, 0); \
        oacc[0][ct] = __builtin_amdgcn_mfma_f32_16x16x32_bf16(a1, pfrag[0][1], oacc[0][ct], 0, 0, 0); \
        oacc[1][ct] = __builtin_amdgcn_mfma_f32_16x16x32_bf16(a0, pfrag[1][0], oacc[1][ct], 0, 0, 0); \
        oacc[1][ct] = __builtin_amdgcn_mfma_f32_16x16x32_bf16(a1, pfrag[1][1], oacc[1][ct], 0, 0, 0); \
    }                                                                        \
    __builtin_amdgcn_s_setprio(0);                                           \
} while (0)

__global__ __launch_bounds__(512, 2) void attn_kernel(const short* __restrict__ X,
                                                      const short* __restrict__ WhT,
                                                      const short* __restrict__ XT,
                                                      short* __restrict__ msgs) {
    __shared__ short kvfA[64 * 256];    // 32 KB
    __shared__ short kvfB[64 * 256];    // 32 KB
    __shared__ short kvTfA[256 * 64];   // 32 KB
    __shared__ short kvTfB[256 * 64];   // 32 KB

    int qt = blockIdx.x, bh = blockIdx.y, b = bh >> 2, h0 = (bh & 3) * 2;
    int tid = threadIdx.x, w = tid >> 6, l = tid & 63, lq = l & 15, quad = l >> 4;
    int q0 = qt * 128;

    const short* Xb   = X  + (size_t)b * N_ * F_;
    const short* XTb  = XT + (size_t)b * F_ * N_;
    const short* Whh0 = WhT + (size_t)h0 * F_ * F_;

    f32x4 oacc[2][16];
    short8 aq[2][8];

    // ---------- phase 0: Q_h = (X qtile @ Wh_h) * SCALE_QK, both heads ------
    // stage X rows q0..q0+127 once: waves 0-3 -> kvfA, waves 4-7 -> kvfB
    {
        short* xdst = (w < 4) ? kvfA : kvfB;
        int wl = w & 3;
#pragma unroll
        for (int i = 0; i < 8; i++) {
            int r = wl * 16 + i * 2 + (l >> 5);
            int bb = (l & 31) ^ (r & 31);
            gld16(&Xb[(size_t)(q0 + ((w >> 2) * 64) + r) * F_ + bb * 8],
                  &xdst[(wl * 16 + i * 2) * 256]);
        }
    }
    const short* xsrc = (w < 4) ? kvfA : kvfB;
#pragma unroll
    for (int hh = 0; hh < 2; hh++) {
#pragma unroll
        for (int i = 0; i < 16; i++) oacc[hh][i] = (f32x4)(0.f);
#pragma unroll 1
        for (int kb = 0; kb < 4; kb++) {
            __syncthreads();   // prev W/aq reads of kvTfA done
#pragma unroll
            for (int i = 0; i < 4; i++) {   // stage WhT[h0+hh][0:256][kb*64..+63] -> kvTfA
                int rt = w * 32 + i * 8 + (l >> 3);
                int bt = (l & 7) ^ (rt & 7);
                gld16(&Whh0[(size_t)(hh * F_ * F_ + rt * F_) + kb * 64 + bt * 8],
                      &kvTfA[(w * 32 + i * 8) * 64]);
            }
            __syncthreads();   // drains DMA (X on first iter, W always)
#pragma unroll
            for (int kk = 0; kk < 2; kk++) {
                int arow = (w & 3) * 16 + lq;
                int ab = (kb * 8 + kk * 4 + quad) ^ (arow & 31);
                short8 af = *(const short8*)&xsrc[arow * 256 + ab * 8];
#pragma unroll
                for (int ct = 0; ct < 16; ct++) {
                    int brow = ct * 16 + lq;
                    int bb = (kk * 4 + quad) ^ (brow & 7);
                    short8 bf = *(const short8*)&kvTfA[brow * 64 + bb * 8];
                    oacc[hh][ct] = __builtin_amdgcn_mfma_f32_16x16x32_bf16(af, bf, oacc[hh][ct], 0, 0, 0);
                }
            }
        }
        __syncthreads();   // all W reads done; reuse kvTfA/B as Q [64 q][256 f]
        {
            short* qdst = (w < 4) ? kvTfA : kvTfB;
#pragma unroll
            for (int ct = 0; ct < 16; ct++) {
#pragma unroll
                for (int r = 0; r < 4; r++) {
                    int row = (w & 3) * 16 + quad * 4 + r;
                    int col = ct * 16 + lq;
                    int pb = (col >> 3) ^ (row & 31);
                    qdst[row * 256 + pb * 8 + (col & 7)] = f2bf(oacc[hh][ct][r] * SCALE_QK);
                }
            }
            __syncthreads();
#pragma unroll
            for (int kk = 0; kk < 8; kk++) {   // aq: B-frag Q[q=(w&3)*16+lq][kk*32+quad*8..]
                int row = (w & 3) * 16 + lq;
                int ab = (kk * 4 + quad) ^ (row & 31);
                aq[hh][kk] = *(const short8*)&qdst[row * 256 + ab * 8];
            }
        }
    }
    __syncthreads();   // all aq reads done before tile-0 DMA overwrites kvTfA

    // ---------- phase 1: pipelined flash attention, 2 heads ----------
#pragma unroll
    for (int hh = 0; hh < 2; hh++)
#pragma unroll
        for (int i = 0; i < 16; i++) oacc[hh][i] = (f32x4)(0.f);
    float m_q[2] = { -INFINITY, -INFINITY }, l_q[2] = { 0.f, 0.f };

    STAGE_KV(0, kvfA, kvTfA);
    __syncthreads();   // drain tile-0 DMA

#pragma unroll 1
    for (int kt2 = 0; kt2 < 16; kt2++) {
        // half A: prefetch tile 2*kt2+1 -> B pair, compute from A pair
        STAGE_KV(2 * kt2 + 1, kvfB, kvTfB);
        COMPUTE_KT(kvfA, kvTfA);
        __syncthreads();   // all A-reads done + B-prefetch (issued pre-compute) drained
        // half B: prefetch tile (2*kt2+2)&31 -> A pair, compute from B pair
        STAGE_KV((2 * kt2 + 2) & 31, kvfA, kvTfA);   // last iter refetches tile 0 (unused, harmless)
        COMPUTE_KT(kvfB, kvTfB);
        __syncthreads();
    }

    // epilogue: per-lane q = q0 + w*16 + lq; feats ct*16 + quad*4 + r
#pragma unroll
    for (int hh = 0; hh < 2; hh++) {
        float inv = 1.f / l_q[hh];
        short* Mout = msgs + (size_t)(b * N_ + q0 + w * 16 + lq) * (H_ * F_) + (h0 + hh) * F_;
#pragma unroll
        for (int ct = 0; ct < 16; ct++) {
            s16x4 v4 = { f2bf(oacc[hh][ct][0] * inv), f2bf(oacc[hh][ct][1] * inv),
                         f2bf(oacc[hh][ct][2] * inv), f2bf(oacc[hh][ct][3] * inv) };
            *(s16x4*)&Mout[ct * 16 + quad * 4] = v4;
        }
    }
}

extern "C" void kernel_launch(void* const* d_in, const int* in_sizes, int n_in,
                              void* d_out, int out_size, void* d_ws, size_t ws_size,
                              hipStream_t stream) {
    const float* nodes = (const float*)d_in[0];   // [4,2048,256] f32
    const float* Wh    = (const float*)d_in[1];   // [8,256,256]  f32
    const float* Wout  = (const float*)d_in[2];   // [2048,256]   f32
    const float* bias  = (const float*)d_in[3];   // [256]        f32
    float* out = (float*)d_out;                   // [4,2048,256] f32

    char* ws = (char*)d_ws;
    short* msgs   = (short*)(ws);                   // [8192][2048] bf16 = 32 MB
    short* WhT    = (short*)(ws + 33554432);        // [8][256][256]       1 MB
    short* WoutT  = (short*)(ws + 34603008);        // [256][2048]         1 MB
    short* XT     = (short*)(ws + 35651584);        // [4][256][2048]      4 MB
    short* Xbf    = (short*)(ws + 39845888);        // [4][2048][256]      4 MB
    short* biasbf = (short*)(ws + 44040192);        // [256]

    dim3 tblk(32, 8, 1);
    hipLaunchKernelGGL(cvtT_kernel, dim3(8, 8, 8),  tblk, 0, stream, Wh,    WhT,   256,  256);
    hipLaunchKernelGGL(cvtT_kernel, dim3(8, 64, 1), tblk, 0, stream, Wout,  WoutT, 2048, 256);
    hipLaunchKernelGGL(cvtT_kernel, dim3(8, 64, 4), tblk, 0, stream, nodes, XT,    2048, 256);
    hipLaunchKernelGGL(cvt_kernel,  dim3(1024), dim3(256), 0, stream, nodes, Xbf, 2097152);
    hipLaunchKernelGGL(cvt_kernel,  dim3(1),    dim3(256), 0, stream, bias, biasbf, 256);

    hipLaunchKernelGGL(attn_kernel, dim3(16, 16), dim3(512), 0, stream, Xbf, WhT, XT, msgs);
    hipLaunchKernelGGL(out_kernel,  dim3(128, 4), dim3(256), 0, stream, msgs, WoutT, biasbf, out);
}

// Round 5
// 343.468 us; speedup vs baseline: 1.8310x; 1.1347x over previous
//
#include <hip/hip_runtime.h>
#include <hip/hip_bf16.h>

#define B_ 4
#define N_ 2048
#define F_ 256
#define H_ 8
#define O_ 256

// log2(e)/16 folded into Q so softmax can use exp2f (exact softmax, monotone map)
#define SCALE_QK 0.09016844005556021f

typedef __attribute__((ext_vector_type(8))) short short8;
typedef __attribute__((ext_vector_type(4))) short s16x4;
typedef __attribute__((ext_vector_type(4))) float f32x4;
typedef __attribute__((ext_vector_type(4))) unsigned int u32x4;

static __device__ __forceinline__ float bf2f(short u) {
    unsigned int x = ((unsigned int)(unsigned short)u) << 16;
    return __builtin_bit_cast(float, x);
}
static __device__ __forceinline__ short f2bf(float f) {
    unsigned int x = __builtin_bit_cast(unsigned int, f);
    unsigned int lsb = (x >> 16) & 1u;
    x += 0x7fffu + lsb;
    return (short)(x >> 16);
}
static __device__ __forceinline__ unsigned int pkbf(float a, float b) {
    return (unsigned int)(unsigned short)f2bf(a) |
           ((unsigned int)(unsigned short)f2bf(b) << 16);
}

// async global->LDS 16B/lane; LDS dst is wave-uniform base + lane*16
static __device__ __forceinline__ void gld16(const short* g, short* l) {
    __builtin_amdgcn_global_load_lds(
        (const __attribute__((address_space(1))) void*)g,
        (__attribute__((address_space(3))) void*)l, 16, 0, 0);
}

// ---- f32 -> bf16 transpose (+ optional straight copy): dstT[c][r] = dst2[r][c] = bf16(src[r][c])
__global__ __launch_bounds__(256) void cvtT_kernel(const float* __restrict__ src,
                                                   short* __restrict__ dstT,
                                                   short* __restrict__ dst2,
                                                   int R, int C) {
    __shared__ short tile[32][33];
    src  += (size_t)blockIdx.z * R * C;
    dstT += (size_t)blockIdx.z * R * C;
    if (dst2) dst2 += (size_t)blockIdx.z * R * C;
    int tx = threadIdx.x, ty = threadIdx.y;           // 32 x 8
    int c0 = blockIdx.x * 32, r0 = blockIdx.y * 32;
#pragma unroll
    for (int j = 0; j < 4; j++) {
        int r = r0 + ty + j * 8;
        short v = f2bf(src[(size_t)r * C + c0 + tx]);
        tile[ty + j * 8][tx] = v;
        if (dst2) dst2[(size_t)r * C + c0 + tx] = v;
    }
    __syncthreads();
#pragma unroll
    for (int j = 0; j < 4; j++) {
        int c = c0 + ty + j * 8;
        dstT[(size_t)c * R + r0 + tx] = tile[tx][ty + j * 8];
    }
}

// ---------------- f32 -> bf16 straight convert (bias only) ----------------
__global__ __launch_bounds__(256) void cvt_kernel(const float* __restrict__ src,
                                                  short* __restrict__ dst, int n) {
    int i = blockIdx.x * 256 + threadIdx.x;
    if (i < n) dst[i] = f2bf(src[i]);
}

// ---- 64-row MFMA GEMM tile, B^T input: C[m][n] = sum_k A[m][k]*Bt[n][k]
template <int NCT>
__device__ __forceinline__ void gemm64_bt(const short* __restrict__ A, int lda,
                                          const short* __restrict__ Bt, int ldb,
                                          float* __restrict__ C, int ldc,
                                          int K, const short* __restrict__ bias) {
    __shared__ short sA[64][72];
    __shared__ short sB[NCT * 16][72];
    int tid = threadIdx.x;
    int w = tid >> 6, l = tid & 63, lq = l & 15, quad = l >> 4;
    f32x4 acc[NCT];
#pragma unroll
    for (int i = 0; i < NCT; i++) acc[i] = (f32x4)(0.f);

    for (int kb = 0; kb < K; kb += 64) {
        __syncthreads();
#pragma unroll
        for (int i = 0; i < 2; i++) {
            int idx = tid + i * 256; int r = idx >> 3, c = (idx & 7) * 8;
            *(short8*)&sA[r][c] = *(const short8*)&A[(size_t)r * lda + kb + c];
        }
#pragma unroll
        for (int i = 0; i < NCT / 2; i++) {
            int idx = tid + i * 256; int r = idx >> 3, c = (idx & 7) * 8;
            *(short8*)&sB[r][c] = *(const short8*)&Bt[(size_t)r * ldb + kb + c];
        }
        __syncthreads();
#pragma unroll
        for (int kk = 0; kk < 2; kk++) {
            short8 af = *(const short8*)&sA[w * 16 + lq][kk * 32 + quad * 8];
#pragma unroll
            for (int ct = 0; ct < NCT; ct++) {
                short8 bf = *(const short8*)&sB[ct * 16 + lq][kk * 32 + quad * 8];
                acc[ct] = __builtin_amdgcn_mfma_f32_16x16x32_bf16(af, bf, acc[ct], 0, 0, 0);
            }
        }
    }
#pragma unroll
    for (int ct = 0; ct < NCT; ct++) {
        int col = ct * 16 + lq;
        float bv = bias ? bf2f(bias[col]) : 0.f;
#pragma unroll
        for (int r = 0; r < 4; r++) {
            int row = w * 16 + quad * 4 + r;
            C[(size_t)row * ldc + col] = acc[ct][r] + bv;
        }
    }
}

// out[m][o] = msgs[m][:] @ Wout + bias; grid (128,4) = 512 blocks -> 2/CU
__global__ __launch_bounds__(256) void out_kernel(const short* __restrict__ msgs,
                                                  const short* __restrict__ WoutT,
                                                  const short* __restrict__ bias,
                                                  float* __restrict__ out) {
    int mt = blockIdx.x, nt = blockIdx.y;
    gemm64_bt<4>(msgs + (size_t)mt * 64 * (H_ * F_), H_ * F_,
                 WoutT + (size_t)nt * 64 * (H_ * F_), H_ * F_,
                 out + (size_t)mt * 64 * O_ + nt * 64, O_,
                 H_ * F_, bias + nt * 64);
}

// ============ fused flash attention, counted-vmcnt pipeline ============
// Block: 512 threads = 8 waves, 128 q (wave w owns q = q0 + w*16 + lq).
// BN=64 keys/iter. Geometry (512 blocks, 1 block/CU, 128 KB LDS) is
// byte-identical to the verified R0 kernel -- R2/R3/R4 showed ANY geometry
// change (2/CU, swizzle, 2-head/256-block) destroys the near-lockstep
// cache reuse (FETCH 41 MB -> 270-910 MB). The only change here is the
// phase-1 sync structure: per tile, {STAGE(next); s_waitcnt vmcnt(8);
// s_barrier; COMPUTE(cur); s_barrier} -- counted vmcnt (T4) waits only the
// 8 OLDEST loads (current tile; vmcnt retires in issue order), so the 8
// next-tile loads stay in flight across the whole compute phase instead of
// being drained by __syncthreads' implicit vmcnt(0).

// stage key-tile KT: K rows into KVF [64][256] (XOR b^(r&31)),
// V^T rows into KVTF [256][64] (XOR b^(r&7)); 8 waves, 8 gld16/lane.
#define STAGE_KV(KT, KVF, KVTF) do {                                         \
    _Pragma("unroll")                                                        \
    for (int i_ = 0; i_ < 4; i_++) {                                         \
        int rk_ = w * 8 + i_ * 2 + (l >> 5);                                 \
        int bk_ = (l & 31) ^ (rk_ & 31);                                     \
        gld16(&Xb[(size_t)((KT) * 64 + rk_) * F_ + bk_ * 8],                 \
              &KVF[(w * 8 + i_ * 2) * 256]);                                 \
        int rt_ = w * 32 + i_ * 8 + (l >> 3);                                \
        int bt_ = (l & 7) ^ (rt_ & 7);                                       \
        gld16(&XTb[(size_t)rt_ * N_ + (KT) * 64 + bt_ * 8],                  \
              &KVTF[(w * 32 + i_ * 8) * 64]);                                \
    }                                                                        \
} while (0)

#define COMPUTE_KT(KVF, KVTF) do {                                           \
    f32x4 sacc[4];                                                           \
    _Pragma("unroll")                                                        \
    for (int ct = 0; ct < 4; ct++) sacc[ct] = (f32x4)(0.f);                  \
    __builtin_amdgcn_s_setprio(1);                                           \
    _Pragma("unroll")                                                        \
    for (int kk = 0; kk < 8; kk++) {                                         \
        _Pragma("unroll")                                                    \
        for (int ct = 0; ct < 4; ct++) {                                     \
            int arow = ct * 16 + lq;                                         \
            int ab = (kk * 4 + quad) ^ (arow & 31);                          \
            short8 af = *(const short8*)&KVF[arow * 256 + ab * 8];           \
            sacc[ct] = __builtin_amdgcn_mfma_f32_16x16x32_bf16(af, aq[kk], sacc[ct], 0, 0, 0); \
        }                                                                    \
    }                                                                        \
    __builtin_amdgcn_s_setprio(0);                                           \
    float mx = -INFINITY;                                                    \
    _Pragma("unroll")                                                        \
    for (int ct = 0; ct < 4; ct++)                                           \
        _Pragma("unroll")                                                    \
        for (int r_ = 0; r_ < 4; r_++) mx = fmaxf(mx, sacc[ct][r_]);         \
    mx = fmaxf(mx, __shfl_xor(mx, 16));                                      \
    mx = fmaxf(mx, __shfl_xor(mx, 32));                                      \
    float mn = fmaxf(m_q, mx);                                               \
    float alpha = exp2f(m_q - mn);                                           \
    m_q = mn;                                                                \
    float pv[4][4]; float s_ = 0.f;                                          \
    _Pragma("unroll")                                                        \
    for (int ct = 0; ct < 4; ct++)                                           \
        _Pragma("unroll")                                                    \
        for (int r_ = 0; r_ < 4; r_++) {                                     \
            pv[ct][r_] = exp2f(sacc[ct][r_] - mn);                           \
            s_ += pv[ct][r_];                                                \
        }                                                                    \
    s_ += __shfl_xor(s_, 16);                                                \
    s_ += __shfl_xor(s_, 32);                                                \
    l_q = l_q * alpha + s_;                                                  \
    if (!__all(alpha == 1.0f)) {                                             \
        _Pragma("unroll")                                                    \
        for (int ct = 0; ct < 16; ct++)                                      \
            _Pragma("unroll")                                                \
            for (int r_ = 0; r_ < 4; r_++) oacc[ct][r_] *= alpha;            \
    }                                                                        \
    unsigned int w2[4][2];                                                   \
    _Pragma("unroll")                                                        \
    for (int ct = 0; ct < 4; ct++) {                                         \
        w2[ct][0] = pkbf(pv[ct][0], pv[ct][1]);                              \
        w2[ct][1] = pkbf(pv[ct][2], pv[ct][3]);                              \
    }                                                                        \
    int sl0 = (2 * (quad & 1)) * 16 + lq;                                    \
    int sl1 = sl0 + 16;                                                      \
    bool hi = (quad >> 1) != 0;                                              \
    short8 pfrag[2];                                                         \
    _Pragma("unroll")                                                        \
    for (int kk = 0; kk < 2; kk++) {                                         \
        unsigned int u0 = __shfl((int)w2[2 * kk][0], sl0);                   \
        unsigned int u1 = __shfl((int)w2[2 * kk][1], sl0);                   \
        unsigned int u2 = __shfl((int)w2[2 * kk][0], sl1);                   \
        unsigned int u3 = __shfl((int)w2[2 * kk][1], sl1);                   \
        unsigned int v0 = __shfl((int)w2[2 * kk + 1][0], sl0);               \
        unsigned int v1 = __shfl((int)w2[2 * kk + 1][1], sl0);               \
        unsigned int v2 = __shfl((int)w2[2 * kk + 1][0], sl1);               \
        unsigned int v3 = __shfl((int)w2[2 * kk + 1][1], sl1);               \
        u32x4 pk = { hi ? v0 : u0, hi ? v1 : u1, hi ? v2 : u2, hi ? v3 : u3 }; \
        pfrag[kk] = __builtin_bit_cast(short8, pk);                          \
    }                                                                        \
    __builtin_amdgcn_s_setprio(1);                                           \
    _Pragma("unroll")                                                        \
    for (int ct = 0; ct < 16; ct++) {                                        \
        int arow = ct * 16 + lq;                                             \
        short8 a0 = *(const short8*)&KVTF[arow * 64 + ((quad) ^ (arow & 7)) * 8]; \
        short8 a1 = *(const short8*)&KVTF[arow * 64 + ((4 + quad) ^ (arow & 7)) * 8]; \
        oacc[ct] = __builtin_amdgcn_mfma_f32_16x16x32_bf16(a0, pfrag[0], oacc[ct], 0, 0, 0); \
        oacc[ct] = __builtin_amdgcn_mfma_f32_16x16x32_bf16(a1, pfrag[1], oacc[ct], 0, 0, 0); \
    }                                                                        \
    __builtin_amdgcn_s_setprio(0);                                           \
} while (0)

__global__ __launch_bounds__(512) void attn_kernel(const short* __restrict__ X,
                                                   const short* __restrict__ WhT,
                                                   const short* __restrict__ XT,
                                                   short* __restrict__ msgs) {
    __shared__ short kvfA[64 * 256];    // 32 KB
    __shared__ short kvfB[64 * 256];    // 32 KB
    __shared__ short kvTfA[256 * 64];   // 32 KB
    __shared__ short kvTfB[256 * 64];   // 32 KB

    int qt = blockIdx.x, bh = blockIdx.y, b = bh >> 3, h = bh & 7;
    int tid = threadIdx.x, w = tid >> 6, l = tid & 63, lq = l & 15, quad = l >> 4;
    int q0 = qt * 128;

    const short* Xb  = X  + (size_t)b * N_ * F_;
    const short* XTb = XT + (size_t)b * F_ * N_;
    const short* Whh = WhT + (size_t)h * F_ * F_;

    f32x4 oacc[16];
    short8 aq[8];

    // ---------- phase 0: Q = (X qtile @ Wh) * SCALE_QK (128 q rows) ----------
#pragma unroll
    for (int i = 0; i < 16; i++) oacc[i] = (f32x4)(0.f);
    {   // stage X rows q0..q0+127: waves 0-3 -> kvfA, waves 4-7 -> kvfB
        short* xdst = (w < 4) ? kvfA : kvfB;
        int wl = w & 3;
#pragma unroll
        for (int i = 0; i < 8; i++) {
            int r = wl * 16 + i * 2 + (l >> 5);
            int bb = (l & 31) ^ (r & 31);
            gld16(&Xb[(size_t)(q0 + ((w >> 2) * 64) + r) * F_ + bb * 8],
                  &xdst[(wl * 16 + i * 2) * 256]);
        }
    }
    const short* xsrc = (w < 4) ? kvfA : kvfB;
#pragma unroll 1
    for (int kb = 0; kb < 4; kb++) {
        __syncthreads();   // prev kb's W reads done
#pragma unroll
        for (int i = 0; i < 4; i++) {   // stage WhT[h][0:256][kb*64..+63] -> kvTfA
            int rt = w * 32 + i * 8 + (l >> 3);
            int bt = (l & 7) ^ (rt & 7);
            gld16(&Whh[(size_t)rt * F_ + kb * 64 + bt * 8], &kvTfA[(w * 32 + i * 8) * 64]);
        }
        __syncthreads();   // drains DMA (X on kb==0, W always)
#pragma unroll
        for (int kk = 0; kk < 2; kk++) {
            int arow = (w & 3) * 16 + lq;
            int ab = (kb * 8 + kk * 4 + quad) ^ (arow & 31);
            short8 af = *(const short8*)&xsrc[arow * 256 + ab * 8];
#pragma unroll
            for (int ct = 0; ct < 16; ct++) {
                int brow = ct * 16 + lq;
                int bb = (kk * 4 + quad) ^ (brow & 7);
                short8 bf = *(const short8*)&kvTfA[brow * 64 + bb * 8];
                oacc[ct] = __builtin_amdgcn_mfma_f32_16x16x32_bf16(af, bf, oacc[ct], 0, 0, 0);
            }
        }
    }
    __syncthreads();   // all W reads done; reuse kvTfA/B as Q [64 q][256 f], XOR b^(r&31)
    {
        short* qdst = (w < 4) ? kvTfA : kvTfB;
#pragma unroll
        for (int ct = 0; ct < 16; ct++) {
#pragma unroll
            for (int r = 0; r < 4; r++) {
                int row = (w & 3) * 16 + quad * 4 + r;
                int col = ct * 16 + lq;
                int pb = (col >> 3) ^ (row & 31);
                qdst[row * 256 + pb * 8 + (col & 7)] = f2bf(oacc[ct][r] * SCALE_QK);
            }
        }
        __syncthreads();
#pragma unroll
        for (int kk = 0; kk < 8; kk++) {   // aq: B-frag Q[q=(w&3)*16+lq][kk*32+quad*8..]
            int row = (w & 3) * 16 + lq;
            int ab = (kk * 4 + quad) ^ (row & 31);
            aq[kk] = *(const short8*)&qdst[row * 256 + ab * 8];
        }
    }
    __syncthreads();   // all aq reads done before tile-0 DMA overwrites kvTfA

    // ---------- phase 1: counted-vmcnt pipelined flash attention ----------
#pragma unroll
    for (int i = 0; i < 16; i++) oacc[i] = (f32x4)(0.f);
    float m_q = -INFINITY, l_q = 0.f;   // state for q = q0 + w*16 + lq

    STAGE_KV(0, kvfA, kvTfA);   // 8 loads in flight (no drain)

#pragma unroll 1
    for (int kt = 0; kt < 32; kt++) {
        const short* KVF  = (kt & 1) ? kvfB  : kvfA;
        const short* KVTF = (kt & 1) ? kvTfB : kvTfA;
        short* nKVF  = (kt & 1) ? kvfA  : kvfB;
        short* nKVTF = (kt & 1) ? kvTfA : kvTfB;
        // issue next tile into the other pair (its readers finished at the
        // trailing barrier of iter kt-1); last iter refetches tile 0 (unused)
        STAGE_KV((kt + 1) & 31, nKVF, nKVTF);          // in flight: 8 cur + 8 next
        asm volatile("s_waitcnt vmcnt(8)" ::: "memory"); // my 8 OLDEST (tile kt) landed
        __builtin_amdgcn_sched_barrier(0);
        __builtin_amdgcn_s_barrier();                   // everyone's tile-kt loads landed
        __builtin_amdgcn_sched_barrier(0);
        COMPUTE_KT(KVF, KVTF);
        __builtin_amdgcn_sched_barrier(0);
        __builtin_amdgcn_s_barrier();                   // all reads of cur pair done
        __builtin_amdgcn_sched_barrier(0);
    }

    // epilogue: per-lane q = q0 + w*16 + lq; feats ct*16 + quad*4 + r
    float inv = 1.f / l_q;
    short* Mout = msgs + (size_t)(b * N_ + q0 + w * 16 + lq) * (H_ * F_) + h * F_;
#pragma unroll
    for (int ct = 0; ct < 16; ct++) {
        s16x4 v4 = { f2bf(oacc[ct][0] * inv), f2bf(oacc[ct][1] * inv),
                     f2bf(oacc[ct][2] * inv), f2bf(oacc[ct][3] * inv) };
        *(s16x4*)&Mout[ct * 16 + quad * 4] = v4;
    }
}

extern "C" void kernel_launch(void* const* d_in, const int* in_sizes, int n_in,
                              void* d_out, int out_size, void* d_ws, size_t ws_size,
                              hipStream_t stream) {
    const float* nodes = (const float*)d_in[0];   // [4,2048,256] f32
    const float* Wh    = (const float*)d_in[1];   // [8,256,256]  f32
    const float* Wout  = (const float*)d_in[2];   // [2048,256]   f32
    const float* bias  = (const float*)d_in[3];   // [256]        f32
    float* out = (float*)d_out;                   // [4,2048,256] f32

    char* ws = (char*)d_ws;
    short* msgs   = (short*)(ws);                   // [8192][2048] bf16 = 32 MB
    short* WhT    = (short*)(ws + 33554432);        // [8][256][256]       1 MB
    short* WoutT  = (short*)(ws + 34603008);        // [256][2048]         1 MB
    short* XT     = (short*)(ws + 35651584);        // [4][256][2048]      4 MB
    short* Xbf    = (short*)(ws + 39845888);        // [4][2048][256]      4 MB
    short* biasbf = (short*)(ws + 44040192);        // [256]

    dim3 tblk(32, 8, 1);
    hipLaunchKernelGGL(cvtT_kernel, dim3(8, 8, 8),  tblk, 0, stream, Wh,    WhT,   (short*)nullptr, 256,  256);
    hipLaunchKernelGGL(cvtT_kernel, dim3(8, 64, 1), tblk, 0, stream, Wout,  WoutT, (short*)nullptr, 2048, 256);
    hipLaunchKernelGGL(cvtT_kernel, dim3(8, 64, 4), tblk, 0, stream, nodes, XT,    Xbf,             2048, 256);
    hipLaunchKernelGGL(cvt_kernel,  dim3(1),    dim3(256), 0, stream, bias, biasbf, 256);

    hipLaunchKernelGGL(attn_kernel, dim3(16, 32), dim3(512), 0, stream, Xbf, WhT, XT, msgs);
    hipLaunchKernelGGL(out_kernel,  dim3(128, 4), dim3(256), 0, stream, msgs, WoutT, biasbf, out);
}

// Round 6
// 289.220 us; speedup vs baseline: 2.1744x; 1.1876x over previous
//
#include <hip/hip_runtime.h>
#include <hip/hip_bf16.h>

#define B_ 4
#define N_ 2048
#define F_ 256
#define H_ 8
#define O_ 256

// log2(e)/16 folded into Q so softmax can use exp2f (exact softmax, monotone map)
#define SCALE_QK 0.09016844005556021f

typedef __attribute__((ext_vector_type(8))) short short8;
typedef __attribute__((ext_vector_type(4))) short s16x4;
typedef __attribute__((ext_vector_type(4))) float f32x4;
typedef __attribute__((ext_vector_type(4))) unsigned int u32x4;

static __device__ __forceinline__ float bf2f(short u) {
    unsigned int x = ((unsigned int)(unsigned short)u) << 16;
    return __builtin_bit_cast(float, x);
}
static __device__ __forceinline__ short f2bf(float f) {
    unsigned int x = __builtin_bit_cast(unsigned int, f);
    unsigned int lsb = (x >> 16) & 1u;
    x += 0x7fffu + lsb;
    return (short)(x >> 16);
}
// packed f32x2 -> bf16x2 in one instruction (RNE); no builtin on gfx950
static __device__ __forceinline__ unsigned int cvtpk(float a, float b) {
    unsigned int r;
    asm("v_cvt_pk_bf16_f32 %0, %1, %2" : "=v"(r) : "v"(a), "v"(b));
    return r;
}

// async global->LDS 16B/lane; LDS dst is wave-uniform base + lane*16
static __device__ __forceinline__ void gld16(const short* g, short* l) {
    __builtin_amdgcn_global_load_lds(
        (const __attribute__((address_space(1))) void*)g,
        (__attribute__((address_space(3))) void*)l, 16, 0, 0);
}

// ---- f32 -> bf16 transpose (+ optional straight copy): dstT[c][r] = dst2[r][c] = bf16(src[r][c])
__global__ __launch_bounds__(256) void cvtT_kernel(const float* __restrict__ src,
                                                   short* __restrict__ dstT,
                                                   short* __restrict__ dst2,
                                                   int R, int C) {
    __shared__ short tile[32][33];
    src  += (size_t)blockIdx.z * R * C;
    dstT += (size_t)blockIdx.z * R * C;
    if (dst2) dst2 += (size_t)blockIdx.z * R * C;
    int tx = threadIdx.x, ty = threadIdx.y;           // 32 x 8
    int c0 = blockIdx.x * 32, r0 = blockIdx.y * 32;
#pragma unroll
    for (int j = 0; j < 4; j++) {
        int r = r0 + ty + j * 8;
        short v = f2bf(src[(size_t)r * C + c0 + tx]);
        tile[ty + j * 8][tx] = v;
        if (dst2) dst2[(size_t)r * C + c0 + tx] = v;
    }
    __syncthreads();
#pragma unroll
    for (int j = 0; j < 4; j++) {
        int c = c0 + ty + j * 8;
        dstT[(size_t)c * R + r0 + tx] = tile[tx][ty + j * 8];
    }
}

// ---------------- f32 -> bf16 straight convert (bias only) ----------------
__global__ __launch_bounds__(256) void cvt_kernel(const float* __restrict__ src,
                                                  short* __restrict__ dst, int n) {
    int i = blockIdx.x * 256 + threadIdx.x;
    if (i < n) dst[i] = f2bf(src[i]);
}

// ---- 64-row MFMA GEMM tile, B^T input: C[m][n] = sum_k A[m][k]*Bt[n][k]
template <int NCT>
__device__ __forceinline__ void gemm64_bt(const short* __restrict__ A, int lda,
                                          const short* __restrict__ Bt, int ldb,
                                          float* __restrict__ C, int ldc,
                                          int K, const short* __restrict__ bias) {
    __shared__ short sA[64][72];
    __shared__ short sB[NCT * 16][72];
    int tid = threadIdx.x;
    int w = tid >> 6, l = tid & 63, lq = l & 15, quad = l >> 4;
    f32x4 acc[NCT];
#pragma unroll
    for (int i = 0; i < NCT; i++) acc[i] = (f32x4)(0.f);

    for (int kb = 0; kb < K; kb += 64) {
        __syncthreads();
#pragma unroll
        for (int i = 0; i < 2; i++) {
            int idx = tid + i * 256; int r = idx >> 3, c = (idx & 7) * 8;
            *(short8*)&sA[r][c] = *(const short8*)&A[(size_t)r * lda + kb + c];
        }
#pragma unroll
        for (int i = 0; i < NCT / 2; i++) {
            int idx = tid + i * 256; int r = idx >> 3, c = (idx & 7) * 8;
            *(short8*)&sB[r][c] = *(const short8*)&Bt[(size_t)r * ldb + kb + c];
        }
        __syncthreads();
#pragma unroll
        for (int kk = 0; kk < 2; kk++) {
            short8 af = *(const short8*)&sA[w * 16 + lq][kk * 32 + quad * 8];
#pragma unroll
            for (int ct = 0; ct < NCT; ct++) {
                short8 bf = *(const short8*)&sB[ct * 16 + lq][kk * 32 + quad * 8];
                acc[ct] = __builtin_amdgcn_mfma_f32_16x16x32_bf16(af, bf, acc[ct], 0, 0, 0);
            }
        }
    }
#pragma unroll
    for (int ct = 0; ct < NCT; ct++) {
        int col = ct * 16 + lq;
        float bv = bias ? bf2f(bias[col]) : 0.f;
#pragma unroll
        for (int r = 0; r < 4; r++) {
            int row = w * 16 + quad * 4 + r;
            C[(size_t)row * ldc + col] = acc[ct][r] + bv;
        }
    }
}

// out[m][o] = msgs[m][:] @ Wout + bias; grid (128,4) = 512 blocks -> 2/CU
__global__ __launch_bounds__(256) void out_kernel(const short* __restrict__ msgs,
                                                  const short* __restrict__ WoutT,
                                                  const short* __restrict__ bias,
                                                  float* __restrict__ out) {
    int mt = blockIdx.x, nt = blockIdx.y;
    gemm64_bt<4>(msgs + (size_t)mt * 64 * (H_ * F_), H_ * F_,
                 WoutT + (size_t)nt * 64 * (H_ * F_), H_ * F_,
                 out + (size_t)mt * 64 * O_ + nt * 64, O_,
                 H_ * F_, bias + nt * 64);
}

// ============ fused flash attention, double-buffered pipeline ============
// Block: 512 threads = 8 waves, 128 q (wave w owns q = q0 + w*16 + lq).
// BN=64 keys/iter. Geometry (512 blocks, grid (16,32), 1 block/CU, 128 KB
// LDS) is byte-identical to the verified R0 kernel -- R2/R3/R4 showed any
// geometry change destroys the lockstep cache reuse (FETCH 41->270-910 MB),
// and R5 showed the counted-vmcnt 2-barrier loop is slower than this
// 1-barrier-per-compute structure (prefetch is issued pre-compute, so the
// barrier's implicit vmcnt(0) drains an already-landed load).
// R6 changes (VALU only, softmax): T13 defer-max THR=8 (skip alpha+64-mul
// oacc rescale unless tile max exceeds running max by >8 in exp2-units;
// P <= 2^8, l_q <= ~5e5, f32-safe, softmax exact) and v_cvt_pk_bf16_f32
// packing (1 inst per bf16x2 vs ~10 for manual-RNE f2bf pair).

// stage key-tile KT: K rows into KVF [64][256] (XOR b^(r&31)),
// V^T rows into KVTF [256][64] (XOR b^(r&7)); 8 waves, 8 gld16/lane.
#define STAGE_KV(KT, KVF, KVTF) do {                                         \
    _Pragma("unroll")                                                        \
    for (int i_ = 0; i_ < 4; i_++) {                                         \
        int rk_ = w * 8 + i_ * 2 + (l >> 5);                                 \
        int bk_ = (l & 31) ^ (rk_ & 31);                                     \
        gld16(&Xb[(size_t)((KT) * 64 + rk_) * F_ + bk_ * 8],                 \
              &KVF[(w * 8 + i_ * 2) * 256]);                                 \
        int rt_ = w * 32 + i_ * 8 + (l >> 3);                                \
        int bt_ = (l & 7) ^ (rt_ & 7);                                       \
        gld16(&XTb[(size_t)rt_ * N_ + (KT) * 64 + bt_ * 8],                  \
              &KVTF[(w * 32 + i_ * 8) * 64]);                                \
    }                                                                        \
} while (0)

#define COMPUTE_KT(KVF, KVTF) do {                                           \
    f32x4 sacc[4];                                                           \
    _Pragma("unroll")                                                        \
    for (int ct = 0; ct < 4; ct++) sacc[ct] = (f32x4)(0.f);                  \
    __builtin_amdgcn_s_setprio(1);                                           \
    _Pragma("unroll")                                                        \
    for (int kk = 0; kk < 8; kk++) {                                         \
        _Pragma("unroll")                                                    \
        for (int ct = 0; ct < 4; ct++) {                                     \
            int arow = ct * 16 + lq;                                         \
            int ab = (kk * 4 + quad) ^ (arow & 31);                          \
            short8 af = *(const short8*)&KVF[arow * 256 + ab * 8];           \
            sacc[ct] = __builtin_amdgcn_mfma_f32_16x16x32_bf16(af, aq[kk], sacc[ct], 0, 0, 0); \
        }                                                                    \
    }                                                                        \
    __builtin_amdgcn_s_setprio(0);                                           \
    float mx = -INFINITY;                                                    \
    _Pragma("unroll")                                                        \
    for (int ct = 0; ct < 4; ct++)                                           \
        _Pragma("unroll")                                                    \
        for (int r_ = 0; r_ < 4; r_++) mx = fmaxf(mx, sacc[ct][r_]);         \
    mx = fmaxf(mx, __shfl_xor(mx, 16));                                      \
    mx = fmaxf(mx, __shfl_xor(mx, 32));                                      \
    if (!__all(mx - m_q <= 8.0f)) {      /* T13 defer-max, THR=8 */          \
        float mn = fmaxf(m_q, mx);                                           \
        float alpha = exp2f(m_q - mn);                                       \
        m_q = mn;                                                            \
        l_q *= alpha;                                                        \
        _Pragma("unroll")                                                    \
        for (int ct = 0; ct < 16; ct++)                                      \
            _Pragma("unroll")                                                \
            for (int r_ = 0; r_ < 4; r_++) oacc[ct][r_] *= alpha;            \
    }                                                                        \
    float pv[4][4]; float s_ = 0.f;                                          \
    _Pragma("unroll")                                                        \
    for (int ct = 0; ct < 4; ct++)                                           \
        _Pragma("unroll")                                                    \
        for (int r_ = 0; r_ < 4; r_++) {                                     \
            pv[ct][r_] = exp2f(sacc[ct][r_] - m_q);                          \
            s_ += pv[ct][r_];                                                \
        }                                                                    \
    s_ += __shfl_xor(s_, 16);                                                \
    s_ += __shfl_xor(s_, 32);                                                \
    l_q += s_;                                                               \
    unsigned int w2[4][2];                                                   \
    _Pragma("unroll")                                                        \
    for (int ct = 0; ct < 4; ct++) {                                         \
        w2[ct][0] = cvtpk(pv[ct][0], pv[ct][1]);                             \
        w2[ct][1] = cvtpk(pv[ct][2], pv[ct][3]);                             \
    }                                                                        \
    int sl0 = (2 * (quad & 1)) * 16 + lq;                                    \
    int sl1 = sl0 + 16;                                                      \
    bool hi = (quad >> 1) != 0;                                              \
    short8 pfrag[2];                                                         \
    _Pragma("unroll")                                                        \
    for (int kk = 0; kk < 2; kk++) {                                         \
        unsigned int u0 = __shfl((int)w2[2 * kk][0], sl0);                   \
        unsigned int u1 = __shfl((int)w2[2 * kk][1], sl0);                   \
        unsigned int u2 = __shfl((int)w2[2 * kk][0], sl1);                   \
        unsigned int u3 = __shfl((int)w2[2 * kk][1], sl1);                   \
        unsigned int v0 = __shfl((int)w2[2 * kk + 1][0], sl0);               \
        unsigned int v1 = __shfl((int)w2[2 * kk + 1][1], sl0);               \
        unsigned int v2 = __shfl((int)w2[2 * kk + 1][0], sl1);               \
        unsigned int v3 = __shfl((int)w2[2 * kk + 1][1], sl1);               \
        u32x4 pk = { hi ? v0 : u0, hi ? v1 : u1, hi ? v2 : u2, hi ? v3 : u3 }; \
        pfrag[kk] = __builtin_bit_cast(short8, pk);                          \
    }                                                                        \
    __builtin_amdgcn_s_setprio(1);                                           \
    _Pragma("unroll")                                                        \
    for (int ct = 0; ct < 16; ct++) {                                        \
        int arow = ct * 16 + lq;                                             \
        short8 a0 = *(const short8*)&KVTF[arow * 64 + ((quad) ^ (arow & 7)) * 8]; \
        short8 a1 = *(const short8*)&KVTF[arow * 64 + ((4 + quad) ^ (arow & 7)) * 8]; \
        oacc[ct] = __builtin_amdgcn_mfma_f32_16x16x32_bf16(a0, pfrag[0], oacc[ct], 0, 0, 0); \
        oacc[ct] = __builtin_amdgcn_mfma_f32_16x16x32_bf16(a1, pfrag[1], oacc[ct], 0, 0, 0); \
    }                                                                        \
    __builtin_amdgcn_s_setprio(0);                                           \
} while (0)

__global__ __launch_bounds__(512) void attn_kernel(const short* __restrict__ X,
                                                   const short* __restrict__ WhT,
                                                   const short* __restrict__ XT,
                                                   short* __restrict__ msgs) {
    __shared__ short kvfA[64 * 256];    // 32 KB
    __shared__ short kvfB[64 * 256];    // 32 KB
    __shared__ short kvTfA[256 * 64];   // 32 KB
    __shared__ short kvTfB[256 * 64];   // 32 KB

    int qt = blockIdx.x, bh = blockIdx.y, b = bh >> 3, h = bh & 7;
    int tid = threadIdx.x, w = tid >> 6, l = tid & 63, lq = l & 15, quad = l >> 4;
    int q0 = qt * 128;

    const short* Xb  = X  + (size_t)b * N_ * F_;
    const short* XTb = XT + (size_t)b * F_ * N_;
    const short* Whh = WhT + (size_t)h * F_ * F_;

    f32x4 oacc[16];
    short8 aq[8];

    // ---------- phase 0: Q = (X qtile @ Wh) * SCALE_QK (128 q rows) ----------
#pragma unroll
    for (int i = 0; i < 16; i++) oacc[i] = (f32x4)(0.f);
    {   // stage X rows q0..q0+127: waves 0-3 -> kvfA, waves 4-7 -> kvfB
        short* xdst = (w < 4) ? kvfA : kvfB;
        int wl = w & 3;
#pragma unroll
        for (int i = 0; i < 8; i++) {
            int r = wl * 16 + i * 2 + (l >> 5);
            int bb = (l & 31) ^ (r & 31);
            gld16(&Xb[(size_t)(q0 + ((w >> 2) * 64) + r) * F_ + bb * 8],
                  &xdst[(wl * 16 + i * 2) * 256]);
        }
    }
    const short* xsrc = (w < 4) ? kvfA : kvfB;
#pragma unroll 1
    for (int kb = 0; kb < 4; kb++) {
        __syncthreads();   // prev kb's W reads done
#pragma unroll
        for (int i = 0; i < 4; i++) {   // stage WhT[h][0:256][kb*64..+63] -> kvTfA
            int rt = w * 32 + i * 8 + (l >> 3);
            int bt = (l & 7) ^ (rt & 7);
            gld16(&Whh[(size_t)rt * F_ + kb * 64 + bt * 8], &kvTfA[(w * 32 + i * 8) * 64]);
        }
        __syncthreads();   // drains DMA (X on kb==0, W always)
#pragma unroll
        for (int kk = 0; kk < 2; kk++) {
            int arow = (w & 3) * 16 + lq;
            int ab = (kb * 8 + kk * 4 + quad) ^ (arow & 31);
            short8 af = *(const short8*)&xsrc[arow * 256 + ab * 8];
#pragma unroll
            for (int ct = 0; ct < 16; ct++) {
                int brow = ct * 16 + lq;
                int bb = (kk * 4 + quad) ^ (brow & 7);
                short8 bf = *(const short8*)&kvTfA[brow * 64 + bb * 8];
                oacc[ct] = __builtin_amdgcn_mfma_f32_16x16x32_bf16(af, bf, oacc[ct], 0, 0, 0);
            }
        }
    }
    __syncthreads();   // all W reads done; reuse kvTfA/B as Q [64 q][256 f], XOR b^(r&31)
    {
        short* qdst = (w < 4) ? kvTfA : kvTfB;
#pragma unroll
        for (int ct = 0; ct < 16; ct++) {
#pragma unroll
            for (int r = 0; r < 4; r++) {
                int row = (w & 3) * 16 + quad * 4 + r;
                int col = ct * 16 + lq;
                int pb = (col >> 3) ^ (row & 31);
                qdst[row * 256 + pb * 8 + (col & 7)] = f2bf(oacc[ct][r] * SCALE_QK);
            }
        }
        __syncthreads();
#pragma unroll
        for (int kk = 0; kk < 8; kk++) {   // aq: B-frag Q[q=(w&3)*16+lq][kk*32+quad*8..]
            int row = (w & 3) * 16 + lq;
            int ab = (kk * 4 + quad) ^ (row & 31);
            aq[kk] = *(const short8*)&qdst[row * 256 + ab * 8];
        }
    }
    __syncthreads();   // all aq reads done before tile-0 DMA overwrites kvTfA

    // ---------- phase 1: pipelined flash attention ----------
#pragma unroll
    for (int i = 0; i < 16; i++) oacc[i] = (f32x4)(0.f);
    float m_q = -INFINITY, l_q = 0.f;   // state for q = q0 + w*16 + lq

    STAGE_KV(0, kvfA, kvTfA);
    __syncthreads();   // drain tile-0 DMA

#pragma unroll 1
    for (int kt2 = 0; kt2 < 16; kt2++) {
        // half A: prefetch tile 2*kt2+1 -> B pair, compute from A pair
        STAGE_KV(2 * kt2 + 1, kvfB, kvTfB);
        COMPUTE_KT(kvfA, kvTfA);
        __syncthreads();   // all A-reads done + B-prefetch (issued pre-compute) drained
        // half B: prefetch tile (2*kt2+2)&31 -> A pair, compute from B pair
        STAGE_KV((2 * kt2 + 2) & 31, kvfA, kvTfA);   // last iter refetches tile 0 (unused, harmless)
        COMPUTE_KT(kvfB, kvTfB);
        __syncthreads();
    }

    // epilogue: per-lane q = q0 + w*16 + lq; feats ct*16 + quad*4 + r
    float inv = 1.f / l_q;
    short* Mout = msgs + (size_t)(b * N_ + q0 + w * 16 + lq) * (H_ * F_) + h * F_;
#pragma unroll
    for (int ct = 0; ct < 16; ct++) {
        s16x4 v4 = { f2bf(oacc[ct][0] * inv), f2bf(oacc[ct][1] * inv),
                     f2bf(oacc[ct][2] * inv), f2bf(oacc[ct][3] * inv) };
        *(s16x4*)&Mout[ct * 16 + quad * 4] = v4;
    }
}

extern "C" void kernel_launch(void* const* d_in, const int* in_sizes, int n_in,
                              void* d_out, int out_size, void* d_ws, size_t ws_size,
                              hipStream_t stream) {
    const float* nodes = (const float*)d_in[0];   // [4,2048,256] f32
    const float* Wh    = (const float*)d_in[1];   // [8,256,256]  f32
    const float* Wout  = (const float*)d_in[2];   // [2048,256]   f32
    const float* bias  = (const float*)d_in[3];   // [256]        f32
    float* out = (float*)d_out;                   // [4,2048,256] f32

    char* ws = (char*)d_ws;
    short* msgs   = (short*)(ws);                   // [8192][2048] bf16 = 32 MB
    short* WhT    = (short*)(ws + 33554432);        // [8][256][256]       1 MB
    short* WoutT  = (short*)(ws + 34603008);        // [256][2048]         1 MB
    short* XT     = (short*)(ws + 35651584);        // [4][256][2048]      4 MB
    short* Xbf    = (short*)(ws + 39845888);        // [4][2048][256]      4 MB
    short* biasbf = (short*)(ws + 44040192);        // [256]

    dim3 tblk(32, 8, 1);
    hipLaunchKernelGGL(cvtT_kernel, dim3(8, 8, 8),  tblk, 0, stream, Wh,    WhT,   (short*)nullptr, 256,  256);
    hipLaunchKernelGGL(cvtT_kernel, dim3(8, 64, 1), tblk, 0, stream, Wout,  WoutT, (short*)nullptr, 2048, 256);
    hipLaunchKernelGGL(cvtT_kernel, dim3(8, 64, 4), tblk, 0, stream, nodes, XT,    Xbf,             2048, 256);
    hipLaunchKernelGGL(cvt_kernel,  dim3(1),    dim3(256), 0, stream, bias, biasbf, 256);

    hipLaunchKernelGGL(attn_kernel, dim3(16, 32), dim3(512), 0, stream, Xbf, WhT, XT, msgs);
    hipLaunchKernelGGL(out_kernel,  dim3(128, 4), dim3(256), 0, stream, msgs, WoutT, biasbf, out);
}

// Round 7
// 289.008 us; speedup vs baseline: 2.1760x; 1.0007x over previous
//
#include <hip/hip_runtime.h>
#include <hip/hip_bf16.h>

#define B_ 4
#define N_ 2048
#define F_ 256
#define H_ 8
#define O_ 256

// log2(e)/16 folded into Q so softmax can use exp2f (exact softmax, monotone map)
#define SCALE_QK 0.09016844005556021f

typedef __attribute__((ext_vector_type(8))) short short8;
typedef __attribute__((ext_vector_type(4))) short s16x4;
typedef __attribute__((ext_vector_type(4))) float f32x4;
typedef __attribute__((ext_vector_type(4))) unsigned int u32x4;

static __device__ __forceinline__ float bf2f(short u) {
    unsigned int x = ((unsigned int)(unsigned short)u) << 16;
    return __builtin_bit_cast(float, x);
}
static __device__ __forceinline__ short f2bf(float f) {
    unsigned int x = __builtin_bit_cast(unsigned int, f);
    unsigned int lsb = (x >> 16) & 1u;
    x += 0x7fffu + lsb;
    return (short)(x >> 16);
}
// packed f32x2 -> bf16x2 in one instruction (RNE); no builtin on gfx950
static __device__ __forceinline__ unsigned int cvtpk(float a, float b) {
    unsigned int r;
    asm("v_cvt_pk_bf16_f32 %0, %1, %2" : "=v"(r) : "v"(a), "v"(b));
    return r;
}

// async global->LDS 16B/lane; LDS dst is wave-uniform base + lane*16
static __device__ __forceinline__ void gld16(const short* g, short* l) {
    __builtin_amdgcn_global_load_lds(
        (const __attribute__((address_space(1))) void*)g,
        (__attribute__((address_space(3))) void*)l, 16, 0, 0);
}

// ---- f32 -> bf16 transpose (+ optional straight copy): dstT[c][r] = dst2[r][c] = bf16(src[r][c])
__global__ __launch_bounds__(256) void cvtT_kernel(const float* __restrict__ src,
                                                   short* __restrict__ dstT,
                                                   short* __restrict__ dst2,
                                                   int R, int C) {
    __shared__ short tile[32][33];
    src  += (size_t)blockIdx.z * R * C;
    dstT += (size_t)blockIdx.z * R * C;
    if (dst2) dst2 += (size_t)blockIdx.z * R * C;
    int tx = threadIdx.x, ty = threadIdx.y;           // 32 x 8
    int c0 = blockIdx.x * 32, r0 = blockIdx.y * 32;
#pragma unroll
    for (int j = 0; j < 4; j++) {
        int r = r0 + ty + j * 8;
        short v = f2bf(src[(size_t)r * C + c0 + tx]);
        tile[ty + j * 8][tx] = v;
        if (dst2) dst2[(size_t)r * C + c0 + tx] = v;
    }
    __syncthreads();
#pragma unroll
    for (int j = 0; j < 4; j++) {
        int c = c0 + ty + j * 8;
        dstT[(size_t)c * R + r0 + tx] = tile[tx][ty + j * 8];
    }
}

// ====== out GEMM: out[m][o] = msgs[m][:2048] @ Wout + bias ======
// 64x128 tile, 512 threads = 8 waves. gld16 staging with pre-swizzled
// source chunks (XOR (l&7)^(l>>3), rule #21 both-sides), XOR-swizzled
// ds_read_b128, double-buffered K-loop with one barrier per K-step
// (same verified loop shape as the attn kernel). Grid (128,2) = 256 blocks.
// Wave w: rows (w&3)*16.. (of 64), cols (w>>2)*64.. (of 128), 4 ct each.
// Bias read directly as f32 in the epilogue (no bf16 prep pass).
__global__ __launch_bounds__(512) void out_kernel(const short* __restrict__ msgs,
                                                  const short* __restrict__ WoutT,
                                                  const float* __restrict__ bias,
                                                  float* __restrict__ out) {
    __shared__ short sA[2][64 * 64];    // 8 KB x2: [64 m][8 chunks of 8 k]
    __shared__ short sB[2][128 * 64];   // 16 KB x2: [128 n][8 chunks of 8 k]
    int mt = blockIdx.x, nt = blockIdx.y;
    int tid = threadIdx.x, w = tid >> 6, l = tid & 63, lq = l & 15, quad = l >> 4;
    const short* Arow = msgs  + (size_t)(mt * 64)  * (H_ * F_);
    const short* Brow = WoutT + (size_t)(nt * 128) * (H_ * F_);
    int xk = (l & 7) ^ (l >> 3);   // pre-swizzled source chunk (row%8 == l>>3)

    f32x4 acc[4];
#pragma unroll
    for (int i = 0; i < 4; i++) acc[i] = (f32x4)(0.f);

    // stage K-chunk KB into buffer BI: A rows w*8..+7 (1 issue), B rows w*16..+15 (2)
#define STAGE_OUT(KB, BI) do {                                               \
        gld16(&Arow[(size_t)(w * 8 + (l >> 3)) * (H_ * F_) + (KB) * 64 + xk * 8], \
              &sA[BI][w * 8 * 64]);                                          \
        gld16(&Brow[(size_t)(w * 16 + (l >> 3)) * (H_ * F_) + (KB) * 64 + xk * 8], \
              &sB[BI][w * 16 * 64]);                                         \
        gld16(&Brow[(size_t)(w * 16 + 8 + (l >> 3)) * (H_ * F_) + (KB) * 64 + xk * 8], \
              &sB[BI][(w * 16 + 8) * 64]);                                   \
    } while (0)

    STAGE_OUT(0, 0);
    __syncthreads();   // drain tile-0 DMA

#pragma unroll 1
    for (int kb = 0; kb < 32; kb++) {
        int cur = kb & 1;
        if (kb < 31) STAGE_OUT(kb + 1, cur ^ 1);   // prefetch next chunk
        int arow = (w & 3) * 16 + lq;
#pragma unroll
        for (int kk = 0; kk < 2; kk++) {
            short8 af = *(const short8*)&sA[cur][arow * 64 + (((kk * 4 + quad) ^ (arow & 7)) * 8)];
#pragma unroll
            for (int ct = 0; ct < 4; ct++) {
                int brow = (w >> 2) * 64 + ct * 16 + lq;
                short8 bf = *(const short8*)&sB[cur][brow * 64 + (((kk * 4 + quad) ^ (brow & 7)) * 8)];
                acc[ct] = __builtin_amdgcn_mfma_f32_16x16x32_bf16(af, bf, acc[ct], 0, 0, 0);
            }
        }
        __syncthreads();   // cur reads done (next iter overwrites) + prefetch drained
    }

#pragma unroll
    for (int ct = 0; ct < 4; ct++) {
        int gcol = nt * 128 + (w >> 2) * 64 + ct * 16 + lq;
        float bv = bias[gcol];
#pragma unroll
        for (int r = 0; r < 4; r++) {
            int row = mt * 64 + (w & 3) * 16 + quad * 4 + r;
            out[(size_t)row * O_ + gcol] = acc[ct][r] + bv;
        }
    }
}

// ============ fused flash attention, double-buffered pipeline ============
// Block: 512 threads = 8 waves, 128 q (wave w owns q = q0 + w*16 + lq).
// BN=64 keys/iter. Geometry (512 blocks, grid (16,32), 1 block/CU, 128 KB
// LDS) is byte-identical to the verified R0 kernel -- R2/R3/R4 showed any
// geometry change destroys the lockstep cache reuse (FETCH 41->270-910 MB),
// and R5 showed the counted-vmcnt 2-barrier loop is slower than this
// 1-barrier-per-compute structure (prefetch is issued pre-compute, so the
// barrier's implicit vmcnt(0) drains an already-landed load).
// R6 (verified): T13 defer-max THR=8 + v_cvt_pk_bf16_f32 packing.
// R7: attn untouched (R6's result pinned the bottleneck to the per-wave
// serial LDS->MFMA->VALU chain, not VALU volume; structural attn changes
// have lost 4 rounds running -- frozen).

// stage key-tile KT: K rows into KVF [64][256] (XOR b^(r&31)),
// V^T rows into KVTF [256][64] (XOR b^(r&7)); 8 waves, 8 gld16/lane.
#define STAGE_KV(KT, KVF, KVTF) do {                                         \
    _Pragma("unroll")                                                        \
    for (int i_ = 0; i_ < 4; i_++) {                                         \
        int rk_ = w * 8 + i_ * 2 + (l >> 5);                                 \
        int bk_ = (l & 31) ^ (rk_ & 31);                                     \
        gld16(&Xb[(size_t)((KT) * 64 + rk_) * F_ + bk_ * 8],                 \
              &KVF[(w * 8 + i_ * 2) * 256]);                                 \
        int rt_ = w * 32 + i_ * 8 + (l >> 3);                                \
        int bt_ = (l & 7) ^ (rt_ & 7);                                       \
        gld16(&XTb[(size_t)rt_ * N_ + (KT) * 64 + bt_ * 8],                  \
              &KVTF[(w * 32 + i_ * 8) * 64]);                                \
    }                                                                        \
} while (0)

#define COMPUTE_KT(KVF, KVTF) do {                                           \
    f32x4 sacc[4];                                                           \
    _Pragma("unroll")                                                        \
    for (int ct = 0; ct < 4; ct++) sacc[ct] = (f32x4)(0.f);                  \
    __builtin_amdgcn_s_setprio(1);                                           \
    _Pragma("unroll")                                                        \
    for (int kk = 0; kk < 8; kk++) {                                         \
        _Pragma("unroll")                                                    \
        for (int ct = 0; ct < 4; ct++) {                                     \
            int arow = ct * 16 + lq;                                         \
            int ab = (kk * 4 + quad) ^ (arow & 31);                          \
            short8 af = *(const short8*)&KVF[arow * 256 + ab * 8];           \
            sacc[ct] = __builtin_amdgcn_mfma_f32_16x16x32_bf16(af, aq[kk], sacc[ct], 0, 0, 0); \
        }                                                                    \
    }                                                                        \
    __builtin_amdgcn_s_setprio(0);                                           \
    float mx = -INFINITY;                                                    \
    _Pragma("unroll")                                                        \
    for (int ct = 0; ct < 4; ct++)                                           \
        _Pragma("unroll")                                                    \
        for (int r_ = 0; r_ < 4; r_++) mx = fmaxf(mx, sacc[ct][r_]);         \
    mx = fmaxf(mx, __shfl_xor(mx, 16));                                      \
    mx = fmaxf(mx, __shfl_xor(mx, 32));                                      \
    if (!__all(mx - m_q <= 8.0f)) {      /* T13 defer-max, THR=8 */          \
        float mn = fmaxf(m_q, mx);                                           \
        float alpha = exp2f(m_q - mn);                                       \
        m_q = mn;                                                            \
        l_q *= alpha;                                                        \
        _Pragma("unroll")                                                    \
        for (int ct = 0; ct < 16; ct++)                                      \
            _Pragma("unroll")                                                \
            for (int r_ = 0; r_ < 4; r_++) oacc[ct][r_] *= alpha;            \
    }                                                                        \
    float pv[4][4]; float s_ = 0.f;                                          \
    _Pragma("unroll")                                                        \
    for (int ct = 0; ct < 4; ct++)                                           \
        _Pragma("unroll")                                                    \
        for (int r_ = 0; r_ < 4; r_++) {                                     \
            pv[ct][r_] = exp2f(sacc[ct][r_] - m_q);                          \
            s_ += pv[ct][r_];                                                \
        }                                                                    \
    s_ += __shfl_xor(s_, 16);                                                \
    s_ += __shfl_xor(s_, 32);                                                \
    l_q += s_;                                                               \
    unsigned int w2[4][2];                                                   \
    _Pragma("unroll")                                                        \
    for (int ct = 0; ct < 4; ct++) {                                         \
        w2[ct][0] = cvtpk(pv[ct][0], pv[ct][1]);                             \
        w2[ct][1] = cvtpk(pv[ct][2], pv[ct][3]);                             \
    }                                                                        \
    int sl0 = (2 * (quad & 1)) * 16 + lq;                                    \
    int sl1 = sl0 + 16;                                                      \
    bool hi = (quad >> 1) != 0;                                              \
    short8 pfrag[2];                                                         \
    _Pragma("unroll")                                                        \
    for (int kk = 0; kk < 2; kk++) {                                         \
        unsigned int u0 = __shfl((int)w2[2 * kk][0], sl0);                   \
        unsigned int u1 = __shfl((int)w2[2 * kk][1], sl0);                   \
        unsigned int u2 = __shfl((int)w2[2 * kk][0], sl1);                   \
        unsigned int u3 = __shfl((int)w2[2 * kk][1], sl1);                   \
        unsigned int v0 = __shfl((int)w2[2 * kk + 1][0], sl0);               \
        unsigned int v1 = __shfl((int)w2[2 * kk + 1][1], sl0);               \
        unsigned int v2 = __shfl((int)w2[2 * kk + 1][0], sl1);               \
        unsigned int v3 = __shfl((int)w2[2 * kk + 1][1], sl1);               \
        u32x4 pk = { hi ? v0 : u0, hi ? v1 : u1, hi ? v2 : u2, hi ? v3 : u3 }; \
        pfrag[kk] = __builtin_bit_cast(short8, pk);                          \
    }                                                                        \
    __builtin_amdgcn_s_setprio(1);                                           \
    _Pragma("unroll")                                                        \
    for (int ct = 0; ct < 16; ct++) {                                        \
        int arow = ct * 16 + lq;                                             \
        short8 a0 = *(const short8*)&KVTF[arow * 64 + ((quad) ^ (arow & 7)) * 8]; \
        short8 a1 = *(const short8*)&KVTF[arow * 64 + ((4 + quad) ^ (arow & 7)) * 8]; \
        oacc[ct] = __builtin_amdgcn_mfma_f32_16x16x32_bf16(a0, pfrag[0], oacc[ct], 0, 0, 0); \
        oacc[ct] = __builtin_amdgcn_mfma_f32_16x16x32_bf16(a1, pfrag[1], oacc[ct], 0, 0, 0); \
    }                                                                        \
    __builtin_amdgcn_s_setprio(0);                                           \
} while (0)

__global__ __launch_bounds__(512) void attn_kernel(const short* __restrict__ X,
                                                   const short* __restrict__ WhT,
                                                   const short* __restrict__ XT,
                                                   short* __restrict__ msgs) {
    __shared__ short kvfA[64 * 256];    // 32 KB
    __shared__ short kvfB[64 * 256];    // 32 KB
    __shared__ short kvTfA[256 * 64];   // 32 KB
    __shared__ short kvTfB[256 * 64];   // 32 KB

    int qt = blockIdx.x, bh = blockIdx.y, b = bh >> 3, h = bh & 7;
    int tid = threadIdx.x, w = tid >> 6, l = tid & 63, lq = l & 15, quad = l >> 4;
    int q0 = qt * 128;

    const short* Xb  = X  + (size_t)b * N_ * F_;
    const short* XTb = XT + (size_t)b * F_ * N_;
    const short* Whh = WhT + (size_t)h * F_ * F_;

    f32x4 oacc[16];
    short8 aq[8];

    // ---------- phase 0: Q = (X qtile @ Wh) * SCALE_QK (128 q rows) ----------
#pragma unroll
    for (int i = 0; i < 16; i++) oacc[i] = (f32x4)(0.f);
    {   // stage X rows q0..q0+127: waves 0-3 -> kvfA, waves 4-7 -> kvfB
        short* xdst = (w < 4) ? kvfA : kvfB;
        int wl = w & 3;
#pragma unroll
        for (int i = 0; i < 8; i++) {
            int r = wl * 16 + i * 2 + (l >> 5);
            int bb = (l & 31) ^ (r & 31);
            gld16(&Xb[(size_t)(q0 + ((w >> 2) * 64) + r) * F_ + bb * 8],
                  &xdst[(wl * 16 + i * 2) * 256]);
        }
    }
    const short* xsrc = (w < 4) ? kvfA : kvfB;
#pragma unroll 1
    for (int kb = 0; kb < 4; kb++) {
        __syncthreads();   // prev kb's W reads done
#pragma unroll
        for (int i = 0; i < 4; i++) {   // stage WhT[h][0:256][kb*64..+63] -> kvTfA
            int rt = w * 32 + i * 8 + (l >> 3);
            int bt = (l & 7) ^ (rt & 7);
            gld16(&Whh[(size_t)rt * F_ + kb * 64 + bt * 8], &kvTfA[(w * 32 + i * 8) * 64]);
        }
        __syncthreads();   // drains DMA (X on kb==0, W always)
#pragma unroll
        for (int kk = 0; kk < 2; kk++) {
            int arow = (w & 3) * 16 + lq;
            int ab = (kb * 8 + kk * 4 + quad) ^ (arow & 31);
            short8 af = *(const short8*)&xsrc[arow * 256 + ab * 8];
#pragma unroll
            for (int ct = 0; ct < 16; ct++) {
                int brow = ct * 16 + lq;
                int bb = (kk * 4 + quad) ^ (brow & 7);
                short8 bf = *(const short8*)&kvTfA[brow * 64 + bb * 8];
                oacc[ct] = __builtin_amdgcn_mfma_f32_16x16x32_bf16(af, bf, oacc[ct], 0, 0, 0);
            }
        }
    }
    __syncthreads();   // all W reads done; reuse kvTfA/B as Q [64 q][256 f], XOR b^(r&31)
    {
        short* qdst = (w < 4) ? kvTfA : kvTfB;
#pragma unroll
        for (int ct = 0; ct < 16; ct++) {
#pragma unroll
            for (int r = 0; r < 4; r++) {
                int row = (w & 3) * 16 + quad * 4 + r;
                int col = ct * 16 + lq;
                int pb = (col >> 3) ^ (row & 31);
                qdst[row * 256 + pb * 8 + (col & 7)] = f2bf(oacc[ct][r] * SCALE_QK);
            }
        }
        __syncthreads();
#pragma unroll
        for (int kk = 0; kk < 8; kk++) {   // aq: B-frag Q[q=(w&3)*16+lq][kk*32+quad*8..]
            int row = (w & 3) * 16 + lq;
            int ab = (kk * 4 + quad) ^ (row & 31);
            aq[kk] = *(const short8*)&qdst[row * 256 + ab * 8];
        }
    }
    __syncthreads();   // all aq reads done before tile-0 DMA overwrites kvTfA

    // ---------- phase 1: pipelined flash attention ----------
#pragma unroll
    for (int i = 0; i < 16; i++) oacc[i] = (f32x4)(0.f);
    float m_q = -INFINITY, l_q = 0.f;   // state for q = q0 + w*16 + lq

    STAGE_KV(0, kvfA, kvTfA);
    __syncthreads();   // drain tile-0 DMA

#pragma unroll 1
    for (int kt2 = 0; kt2 < 16; kt2++) {
        // half A: prefetch tile 2*kt2+1 -> B pair, compute from A pair
        STAGE_KV(2 * kt2 + 1, kvfB, kvTfB);
        COMPUTE_KT(kvfA, kvTfA);
        __syncthreads();   // all A-reads done + B-prefetch (issued pre-compute) drained
        // half B: prefetch tile (2*kt2+2)&31 -> A pair, compute from B pair
        STAGE_KV((2 * kt2 + 2) & 31, kvfA, kvTfA);   // last iter refetches tile 0 (unused, harmless)
        COMPUTE_KT(kvfB, kvTfB);
        __syncthreads();
    }

    // epilogue: per-lane q = q0 + w*16 + lq; feats ct*16 + quad*4 + r
    float inv = 1.f / l_q;
    short* Mout = msgs + (size_t)(b * N_ + q0 + w * 16 + lq) * (H_ * F_) + h * F_;
#pragma unroll
    for (int ct = 0; ct < 16; ct++) {
        s16x4 v4 = { f2bf(oacc[ct][0] * inv), f2bf(oacc[ct][1] * inv),
                     f2bf(oacc[ct][2] * inv), f2bf(oacc[ct][3] * inv) };
        *(s16x4*)&Mout[ct * 16 + quad * 4] = v4;
    }
}

extern "C" void kernel_launch(void* const* d_in, const int* in_sizes, int n_in,
                              void* d_out, int out_size, void* d_ws, size_t ws_size,
                              hipStream_t stream) {
    const float* nodes = (const float*)d_in[0];   // [4,2048,256] f32
    const float* Wh    = (const float*)d_in[1];   // [8,256,256]  f32
    const float* Wout  = (const float*)d_in[2];   // [2048,256]   f32
    const float* bias  = (const float*)d_in[3];   // [256]        f32
    float* out = (float*)d_out;                   // [4,2048,256] f32

    char* ws = (char*)d_ws;
    short* msgs   = (short*)(ws);                   // [8192][2048] bf16 = 32 MB
    short* WhT    = (short*)(ws + 33554432);        // [8][256][256]       1 MB
    short* WoutT  = (short*)(ws + 34603008);        // [256][2048]         1 MB
    short* XT     = (short*)(ws + 35651584);        // [4][256][2048]      4 MB
    short* Xbf    = (short*)(ws + 39845888);        // [4][2048][256]      4 MB

    dim3 tblk(32, 8, 1);
    hipLaunchKernelGGL(cvtT_kernel, dim3(8, 8, 8),  tblk, 0, stream, Wh,    WhT,   (short*)nullptr, 256,  256);
    hipLaunchKernelGGL(cvtT_kernel, dim3(8, 64, 1), tblk, 0, stream, Wout,  WoutT, (short*)nullptr, 2048, 256);
    hipLaunchKernelGGL(cvtT_kernel, dim3(8, 64, 4), tblk, 0, stream, nodes, XT,    Xbf,             2048, 256);

    hipLaunchKernelGGL(attn_kernel, dim3(16, 32), dim3(512), 0, stream, Xbf, WhT, XT, msgs);
    hipLaunchKernelGGL(out_kernel,  dim3(128, 2), dim3(512), 0, stream, msgs, WoutT, bias, out);
}